// Round 17
// baseline (243.350 us; speedup 1.0000x reference)
//
#include <hip/hip_runtime.h>

#define NPB_SHIFT 8
#define NPB 256          // nodes per bucket
#define EPB 4096         // edges per partition block (782 blocks, 32KB LDS)
#define EPT 16           // edges per thread in partition (EPB/256)
#define MAXB 512         // padded bucket count (NB = ceil(100000/256) = 391)
#define BCAP 9216        // fixed bucket capacity: E/NB=8184, sigma~90 -> +11 sigma
#define SRC_BITS 17      // N=100000 < 2^17
#define SRC_MASK 0x1FFFFu

// ---------------- K3: single-pass LDS-staged partition (register-held ranks) ----------------
__global__ __launch_bounds__(256) void partition_kernel(const int* __restrict__ src,
                                                        const int* __restrict__ dst,
                                                        unsigned int* __restrict__ bcur,
                                                        unsigned int* __restrict__ staged, int E, int NB) {
    __shared__ unsigned int hist[MAXB], sc[MAXB], lbase[MAXB], gbase[MAXB];
    __shared__ unsigned int stage[EPB];
    __shared__ unsigned short sbuck[EPB];
    int start = blockIdx.x * EPB;
    int cnt = min(EPB, E - start);
    for (int j = threadIdx.x; j < MAXB; j += 256) hist[j] = 0u;
    __syncthreads();

    unsigned int rec[EPT], rnk[EPT], bkt[EPT];
#pragma unroll
    for (int u = 0; u < EPT; ++u) {
        int k = u * 256 + threadIdx.x;
        if (k < cnt) {
            unsigned int d = (unsigned int)dst[start + k];
            unsigned int s = (unsigned int)src[start + k];
            unsigned int b = d >> NPB_SHIFT;
            rec[u] = ((d & (NPB - 1)) << SRC_BITS) | s;
            bkt[u] = b;
            rnk[u] = atomicAdd(&hist[b], 1u);   // in-bucket rank, single pass
        }
    }
    __syncthreads();
    {
        int i0 = threadIdx.x, i1 = threadIdx.x + 256;
        sc[i0] = hist[i0]; sc[i1] = hist[i1];
        __syncthreads();
        for (int o = 1; o < MAXB; o <<= 1) {
            unsigned int v0 = (i0 >= o) ? sc[i0 - o] : 0u;
            unsigned int v1 = (i1 >= o) ? sc[i1 - o] : 0u;
            __syncthreads();
            sc[i0] += v0; sc[i1] += v1;
            __syncthreads();
        }
    }
    for (int j = threadIdx.x; j < MAXB; j += 256) {
        unsigned int c = hist[j];
        lbase[j] = sc[j] - c;
        gbase[j] = (j < NB && c) ? atomicAdd(&bcur[j], c) : 0u;
    }
    __syncthreads();
#pragma unroll
    for (int u = 0; u < EPT; ++u) {
        int k = u * 256 + threadIdx.x;
        if (k < cnt) {
            unsigned int pos = lbase[bkt[u]] + rnk[u];
            stage[pos] = rec[u];
            sbuck[pos] = (unsigned short)bkt[u];
        }
    }
    __syncthreads();
    for (int t = threadIdx.x; t < cnt; t += 256) {
        unsigned int b = sbuck[t];
        staged[(size_t)gbase[b] + (t - lbase[b])] = stage[t];
    }
}

// ---------------- K4: per-bucket exact CSR + off/deg/dinv/ttx ----------------
__global__ __launch_bounds__(256) void build_csr_kernel(const unsigned int* __restrict__ staged,
                                                        const unsigned int* __restrict__ bcur,
                                                        const float* __restrict__ x,
                                                        unsigned int* __restrict__ csr,
                                                        unsigned int* __restrict__ off,
                                                        unsigned int* __restrict__ deg,
                                                        float* __restrict__ dinv,
                                                        float* __restrict__ ttx, int N) {
    __shared__ unsigned int cnt[NPB], loff[NPB], ncur[NPB];
    int b = blockIdx.x;
    unsigned int base = (unsigned int)b * BCAP;
    unsigned int m = bcur[b] - base;
    int node0 = b << NPB_SHIFT;
    cnt[threadIdx.x] = 0u;
    __syncthreads();
    for (unsigned int t = threadIdx.x; t < m; t += 256)
        atomicAdd(&cnt[staged[(size_t)base + t] >> SRC_BITS], 1u);
    __syncthreads();
    unsigned int v = cnt[threadIdx.x];
    loff[threadIdx.x] = v;
    __syncthreads();
    for (int o = 1; o < NPB; o <<= 1) {
        unsigned int a = (threadIdx.x >= (unsigned)o) ? loff[threadIdx.x - o] : 0u;
        __syncthreads();
        loff[threadIdx.x] += a;
        __syncthreads();
    }
    unsigned int ex = loff[threadIdx.x] - v;
    ncur[threadIdx.x] = ex;
    int node = node0 + threadIdx.x;
    if (node < N) {
        off[node] = base + ex;
        deg[node] = v;
        float di = 1.0f / sqrtf((float)(v + 1u));  // +1 self loop
        dinv[node] = di;
        ttx[node] = di * x[node];
    }
    __syncthreads();
    for (unsigned int t = threadIdx.x; t < m; t += 256) {
        unsigned int rec = staged[(size_t)base + t];
        unsigned int p = atomicAdd(&ncur[rec >> SRC_BITS], 1u);
        csr[(size_t)base + p] = rec & SRC_MASK;
    }
}

// ---------------- LUT build (65 blocks); block 0 also inits bcur ----------------
__global__ __launch_bounds__(256) void lut_kernel(const float* __restrict__ W1, const float* __restrict__ b1,
                                                  const float* __restrict__ W2,
                                                  float* __restrict__ Alut, float* __restrict__ Blut,
                                                  float* __restrict__ tvals,
                                                  unsigned int* __restrict__ bcur, int NB) {
    __shared__ float w1[64], bb[64], tv[64];
    __shared__ int rnk[64];
    __shared__ float sW2[64 * 32];
    __shared__ double red[2][256];
    int tid = threadIdx.x;
    if (blockIdx.x == 0) {
        for (int t = tid; t < NB; t += 256) bcur[t] = (unsigned int)t * BCAP;
    }
    if (tid < 64) {
        float w = W1[tid], b = b1[tid];
        w1[tid] = w; bb[tid] = b;
        tv[tid] = (w != 0.f) ? (-b / w) : __uint_as_float(0x7F800000u);  // +inf for degenerate
    }
    for (int t = tid; t < 64 * 32; t += 256) sW2[t] = W2[t];
    __syncthreads();
    if (tid < 64) {
        int r = 0;
        float tj = tv[tid];
        for (int k = 0; k < 64; ++k)
            if (w1[k] != 0.f && (tv[k] < tj || (tv[k] == tj && k < tid))) ++r;
        rnk[tid] = r;
        if (blockIdx.x == 0) tvals[tid] = tv[tid];
    }
    __syncthreads();
    int s = blockIdx.x;                 // segment 0..64
    int c = tid & 31, slice = tid >> 5; // 8 j-slices x 32 channels
    double da = 0.0, db = 0.0;
#pragma unroll
    for (int u = 0; u < 8; ++u) {
        int j = slice * 8 + u;
        float w = w1[j];
        bool act = (w > 0.f) ? (rnk[j] < s) : ((w < 0.f) ? (rnk[j] >= s) : (bb[j] > 0.f));
        if (act) {
            double w2 = (double)sW2[j * 32 + c];
            da += (double)w * w2;
            db += (double)bb[j] * w2;
        }
    }
    red[0][tid] = da; red[1][tid] = db;
    __syncthreads();
    for (int o = 128; o >= 32; o >>= 1) {
        if (tid < o) { red[0][tid] += red[0][tid + o]; red[1][tid] += red[1][tid + o]; }
        __syncthreads();
    }
    if (tid < 32) {
        Alut[s * 32 + tid] = (float)red[0][tid];
        Blut[s * 32 + tid] = (float)red[1][tid];
    }
}

// ---------------- layer-1 gather + fused segment classification -> recs ----------------
__global__ __launch_bounds__(256) void gather1_kernel(const unsigned int* __restrict__ csr,
                                                      const unsigned int* __restrict__ off,
                                                      const unsigned int* __restrict__ deg,
                                                      const float* __restrict__ dinv,
                                                      const float* __restrict__ tt,
                                                      const float* __restrict__ tvals,
                                                      uint4* __restrict__ recs, int N) {
    __shared__ float st[64];
    for (int t = threadIdx.x; t < 64; t += 256) st[t] = tvals[t];
    __syncthreads();
    int tid = blockIdx.x * 256 + threadIdx.x;
    int i = tid >> 2, l = tid & 3;
    if (i >= N) return;
    unsigned int o = off[i], n = deg[i];
    float acc0 = 0.f, acc1 = 0.f;
    unsigned int k = l;
    for (; k + 4 < n; k += 8) { acc0 += tt[csr[o + k]]; acc1 += tt[csr[o + k + 4]]; }
    if (k < n) acc0 += tt[csr[o + k]];
    float acc = acc0 + acc1;
    acc += __shfl_xor(acc, 1, 4);
    acc += __shfl_xor(acc, 2, 4);
    float di = dinv[i];
    float a = di * (acc + tt[i]);        // agg1 (all 4 lanes hold it)
    unsigned int cv = 0;
#pragma unroll
    for (int j = 0; j < 16; ++j) cv += (st[l * 16 + j] < a) ? 1u : 0u;
    cv += __shfl_xor(cv, 1, 4);
    cv += __shfl_xor(cv, 2, 4);
    if (l == 0) recs[i] = make_uint4(__float_as_uint(a * di), __float_as_uint(di), cv, 0u);
}

// ---------------- layer-2 LUT gather + in-register shuffle transform -> tt3 ----------------
#define G2_ITERS 4
#define FMA4(R, ACC)                                                          \
    {                                                                         \
        float4 A_ = sA2[(R).z * 8 + cc], B_ = sB2[(R).z * 8 + cc];            \
        float p_ = __uint_as_float((R).x), q_ = __uint_as_float((R).y);       \
        (ACC).x = fmaf(A_.x, p_, fmaf(B_.x, q_, (ACC).x));                    \
        (ACC).y = fmaf(A_.y, p_, fmaf(B_.y, q_, (ACC).y));                    \
        (ACC).z = fmaf(A_.z, p_, fmaf(B_.z, q_, (ACC).z));                    \
        (ACC).w = fmaf(A_.w, p_, fmaf(B_.w, q_, (ACC).w));                    \
    }
__global__ __launch_bounds__(256) void gather2t3_kernel(const unsigned int* __restrict__ csr,
                                                        const unsigned int* __restrict__ off,
                                                        const unsigned int* __restrict__ deg,
                                                        const float* __restrict__ dinv,
                                                        const uint4* __restrict__ recs,
                                                        const float* __restrict__ Alut, const float* __restrict__ Blut,
                                                        const float* __restrict__ b2, const float* __restrict__ W3,
                                                        float* __restrict__ tt3, int N) {
    __shared__ float4 sA2[65 * 8], sB2[65 * 8];
    __shared__ float2 sW3p[32 * 8];
    __shared__ float sb2[32];
    for (int t = threadIdx.x; t < 65 * 8; t += 256) {
        int s = t >> 3, q = t & 7;
        sA2[t] = make_float4(Alut[s * 32 + q], Alut[s * 32 + q + 8],
                             Alut[s * 32 + q + 16], Alut[s * 32 + q + 24]);
        sB2[t] = make_float4(Blut[s * 32 + q], Blut[s * 32 + q + 8],
                             Blut[s * 32 + q + 16], Blut[s * 32 + q + 24]);
    }
    for (int t = threadIdx.x; t < 32 * 8; t += 256) {
        int k = t >> 3, q = t & 7;
        sW3p[t] = make_float2(W3[k * 16 + q], W3[k * 16 + q + 8]);
    }
    if (threadIdx.x < 32) sb2[threadIdx.x] = b2[threadIdx.x];
    __syncthreads();

    int g = threadIdx.x >> 3, cc = threadIdx.x & 7;
    for (int iter = 0; iter < G2_ITERS; ++iter) {
        int d = blockIdx.x * (32 * G2_ITERS) + iter * 32 + g;
        if (d >= N) continue;
        float dd = dinv[d];
        unsigned int o = off[d], n = deg[d];
        uint4 rs = recs[d];
        float ps = __uint_as_float(rs.x), qs = __uint_as_float(rs.y);
        float4 As = sA2[rs.z * 8 + cc], Bs = sB2[rs.z * 8 + cc];
        float4 aP, aQ;
        aP.x = fmaf(As.x, ps, Bs.x * qs); aP.y = fmaf(As.y, ps, Bs.y * qs);
        aP.z = fmaf(As.z, ps, Bs.z * qs); aP.w = fmaf(As.w, ps, Bs.w * qs);
        aQ = make_float4(0.f, 0.f, 0.f, 0.f);
        unsigned int P = n >> 1;
        if (P >= 2) {
            unsigned int c0 = csr[o], c1 = csr[o + 1];
            unsigned int c2 = csr[o + 2], c3 = csr[o + 3];
            uint4 r0 = recs[c0], r1 = recs[c1];
            for (unsigned int j = 0; j + 2 < P; ++j) {
                unsigned int base = o + 2 * j;
                unsigned int nc0 = csr[base + 4], nc1 = csr[base + 5];
                uint4 nr0 = recs[c2], nr1 = recs[c3];
                FMA4(r0, aP); FMA4(r1, aQ);
                r0 = nr0; r1 = nr1; c2 = nc0; c3 = nc1;
            }
            uint4 m0 = recs[c2], m1 = recs[c3];
            FMA4(r0, aP); FMA4(r1, aQ);
            FMA4(m0, aP); FMA4(m1, aQ);
        } else if (P == 1) {
            uint4 r0 = recs[csr[o]], r1 = recs[csr[o + 1]];
            FMA4(r0, aP); FMA4(r1, aQ);
        }
        if (n & 1u) {
            uint4 r0 = recs[csr[o + n - 1]];
            FMA4(r0, aP);
        }
        float hv0 = fmaxf(fmaf(dd, aP.x + aQ.x, sb2[cc]), 0.f);
        float hv1 = fmaxf(fmaf(dd, aP.y + aQ.y, sb2[cc + 8]), 0.f);
        float hv2 = fmaxf(fmaf(dd, aP.z + aQ.z, sb2[cc + 16]), 0.f);
        float hv3 = fmaxf(fmaf(dd, aP.w + aQ.w, sb2[cc + 24]), 0.f);

        float t0 = 0.f, t1 = 0.f;
#pragma unroll
        for (int l2 = 0; l2 < 8; ++l2) {
            float hk = __shfl(hv0, l2, 8);
            float2 w = sW3p[l2 * 8 + cc];
            t0 = fmaf(hk, w.x, t0); t1 = fmaf(hk, w.y, t1);
        }
#pragma unroll
        for (int l2 = 0; l2 < 8; ++l2) {
            float hk = __shfl(hv1, l2, 8);
            float2 w = sW3p[(8 + l2) * 8 + cc];
            t0 = fmaf(hk, w.x, t0); t1 = fmaf(hk, w.y, t1);
        }
#pragma unroll
        for (int l2 = 0; l2 < 8; ++l2) {
            float hk = __shfl(hv2, l2, 8);
            float2 w = sW3p[(16 + l2) * 8 + cc];
            t0 = fmaf(hk, w.x, t0); t1 = fmaf(hk, w.y, t1);
        }
#pragma unroll
        for (int l2 = 0; l2 < 8; ++l2) {
            float hk = __shfl(hv3, l2, 8);
            float2 w = sW3p[(24 + l2) * 8 + cc];
            t0 = fmaf(hk, w.x, t0); t1 = fmaf(hk, w.y, t1);
        }
        tt3[(size_t)d * 16 + cc] = dd * t0;
        tt3[(size_t)d * 16 + cc + 8] = dd * t1;
    }
}

// ---------------- layer-3 gather, CHANNEL-HALF pass (8 ch = 3.2MB slab, L2-fits) ----------------
// 2 lanes/node; lane reads float4 idx (d*4 + 2*half + l). HALF=0 writes partial;
// HALF=1 adds channels 8..15 and writes tt4 = dd*(partial + s).
template<int HALF>
__global__ __launch_bounds__(256) void gather3t4_half_kernel(const unsigned int* __restrict__ csr,
                                                             const unsigned int* __restrict__ off,
                                                             const unsigned int* __restrict__ deg,
                                                             const float* __restrict__ dinv,
                                                             const float* __restrict__ tt3,
                                                             const float* __restrict__ b3, const float* __restrict__ W4,
                                                             float* __restrict__ partial,
                                                             float* __restrict__ tt4, int N) {
    int tid = blockIdx.x * 256 + threadIdx.x;
    int d = tid >> 1, l = tid & 1;
    if (d >= N) return;
    float dd = dinv[d];
    unsigned int o = off[d], n = deg[d];
    const float4* t34 = reinterpret_cast<const float4*>(tt3);
    const int fi = 2 * HALF + l;           // float4 index within row
    float4 acc = t34[(size_t)d * 4 + fi];  // self term
    float4 acc1 = make_float4(0.f, 0.f, 0.f, 0.f);
    unsigned int k = 0;
    if (n >= 2) {
        unsigned int s0 = csr[o], s1 = csr[o + 1];
        k = 2;
        for (; k + 1 < n; k += 2) {
            unsigned int t0 = csr[o + k], t1 = csr[o + k + 1];   // csr 1 pair ahead
            float4 v0 = t34[(size_t)s0 * 4 + fi];
            float4 v1 = t34[(size_t)s1 * 4 + fi];
            acc.x += v0.x; acc.y += v0.y; acc.z += v0.z; acc.w += v0.w;
            acc1.x += v1.x; acc1.y += v1.y; acc1.z += v1.z; acc1.w += v1.w;
            s0 = t0; s1 = t1;
        }
        {
            float4 v0 = t34[(size_t)s0 * 4 + fi];
            float4 v1 = t34[(size_t)s1 * 4 + fi];
            acc.x += v0.x; acc.y += v0.y; acc.z += v0.z; acc.w += v0.w;
            acc1.x += v1.x; acc1.y += v1.y; acc1.z += v1.z; acc1.w += v1.w;
        }
    }
    if (k < n) {
        float4 v0 = t34[(size_t)csr[o + k] * 4 + fi];
        acc.x += v0.x; acc.y += v0.y; acc.z += v0.z; acc.w += v0.w;
    }
    acc.x += acc1.x; acc.y += acc1.y; acc.z += acc1.z; acc.w += acc1.w;
    float4 b3v = reinterpret_cast<const float4*>(b3)[fi];
    float4 w4v = reinterpret_cast<const float4*>(W4)[fi];
    float v = fmaxf(fmaf(dd, acc.x, b3v.x), 0.f) * w4v.x;
    v = fmaf(fmaxf(fmaf(dd, acc.y, b3v.y), 0.f), w4v.y, v);
    v = fmaf(fmaxf(fmaf(dd, acc.z, b3v.z), 0.f), w4v.z, v);
    v = fmaf(fmaxf(fmaf(dd, acc.w, b3v.w), 0.f), w4v.w, v);
    v += __shfl_xor(v, 1, 2);
    if (l == 0) {
        if (HALF == 0) partial[d] = v;
        else           tt4[d] = dd * (partial[d] + v);
    }
}

// ---------------- layer-4 scalar gather -> out ----------------
__global__ void gather4_kernel(const unsigned int* __restrict__ csr, const unsigned int* __restrict__ off,
                               const unsigned int* __restrict__ deg, const float* __restrict__ dinv,
                               const float* __restrict__ tt, const float* __restrict__ b4,
                               float* __restrict__ out, int N) {
    int tid = blockIdx.x * blockDim.x + threadIdx.x;
    int i = tid >> 2, l = tid & 3;
    if (i >= N) return;
    unsigned int o = off[i], n = deg[i];
    float acc0 = 0.f, acc1 = 0.f;
    unsigned int k = l;
    for (; k + 4 < n; k += 8) { acc0 += tt[csr[o + k]]; acc1 += tt[csr[o + k + 4]]; }
    if (k < n) acc0 += tt[csr[o + k]];
    float acc = acc0 + acc1;
    acc += __shfl_xor(acc, 1, 4);
    acc += __shfl_xor(acc, 2, 4);
    if (l == 0) out[i] = dinv[i] * (acc + tt[i]) + b4[0];
}

extern "C" void kernel_launch(void* const* d_in, const int* in_sizes, int n_in,
                              void* d_out, int out_size, void* d_ws, size_t ws_size,
                              hipStream_t stream) {
    const float* x  = (const float*)d_in[0];
    const int* eidx = (const int*)d_in[1];
    const float* W1 = (const float*)d_in[2];
    const float* b1 = (const float*)d_in[3];
    const float* W2 = (const float*)d_in[4];
    const float* b2 = (const float*)d_in[5];
    const float* W3 = (const float*)d_in[6];
    const float* b3 = (const float*)d_in[7];
    const float* W4 = (const float*)d_in[8];
    const float* b4 = (const float*)d_in[9];
    float* out = (float*)d_out;

    const int N = in_sizes[0];         // 100000
    const int E = in_sizes[1] / 2;     // 3200000
    const int* src = eidx;
    const int* dst = eidx + E;
    const int NB = (N + NPB - 1) >> NPB_SHIFT;   // 391 buckets

    char* ws = (char*)d_ws;
    unsigned int* bcur  = (unsigned int*)ws;  ws += MAXB * 4;
    float* tvals = (float*)ws;                ws += 64 * 4;
    float* Alut  = (float*)ws;                ws += 65 * 32 * 4;
    float* Blut  = (float*)ws;                ws += 65 * 32 * 4;
    unsigned int* off = (unsigned int*)ws;    ws += (size_t)N * 4;
    unsigned int* deg = (unsigned int*)ws;    ws += (size_t)N * 4;
    float* dinv = (float*)ws;                 ws += (size_t)N * 4;
    float* ttx  = (float*)ws;                 ws += (size_t)N * 4;
    float* tt4  = (float*)ws;                 ws += (size_t)N * 4;
    float* part = (float*)ws;                 ws += (size_t)N * 4;
    uint4* recs = (uint4*)ws;                 ws += (size_t)N * 16;
    unsigned int* csr = (unsigned int*)ws;    ws += (size_t)NB * BCAP * 4;   // padded CSR (14.4MB)
    unsigned int* staged = (unsigned int*)ws; // padded staged; tt3 (6.4MB) aliases it
    float* tt3 = (float*)staged;              // staged dead after build_csr

    const int nPartBlocks = (E + EPB - 1) / EPB;   // 782

    lut_kernel<<<65, 256, 0, stream>>>(W1, b1, W2, Alut, Blut, tvals, bcur, NB);
    partition_kernel<<<nPartBlocks, 256, 0, stream>>>(src, dst, bcur, staged, E, NB);
    build_csr_kernel<<<NB, 256, 0, stream>>>(staged, bcur, x, csr, off, deg, dinv, ttx, N);

    gather1_kernel<<<((size_t)N * 4 + 255) / 256, 256, 0, stream>>>(csr, off, deg, dinv, ttx, tvals, recs, N);
    gather2t3_kernel<<<(N + 32 * G2_ITERS - 1) / (32 * G2_ITERS), 256, 0, stream>>>(csr, off, deg, dinv, recs, Alut, Blut, b2, W3, tt3, N);
    gather3t4_half_kernel<0><<<((size_t)N * 2 + 255) / 256, 256, 0, stream>>>(csr, off, deg, dinv, tt3, b3, W4, part, tt4, N);
    gather3t4_half_kernel<1><<<((size_t)N * 2 + 255) / 256, 256, 0, stream>>>(csr, off, deg, dinv, tt3, b3, W4, part, tt4, N);
    gather4_kernel<<<((size_t)N * 4 + 255) / 256, 256, 0, stream>>>(csr, off, deg, dinv, tt4, b4, out, N);
}

// Round 18
// 217.758 us; speedup vs baseline: 1.1175x; 1.1175x over previous
//
#include <hip/hip_runtime.h>

#define NPB_SHIFT 8
#define NPB 256          // nodes per bucket
#define EPB 4096         // edges per partition block (782 blocks, 32KB LDS)
#define EPT 16           // edges per thread in partition (EPB/256)
#define MAXB 512         // padded bucket count (NB = ceil(100000/256) = 391)
#define BCAP 9216        // fixed bucket capacity: E/NB=8184, sigma~90 -> +11 sigma
#define SRC_BITS 17      // N=100000 < 2^17
#define SRC_MASK 0x1FFFFu

// ---------------- K3: single-pass LDS-staged partition (register-held ranks) ----------------
__global__ __launch_bounds__(256) void partition_kernel(const int* __restrict__ src,
                                                        const int* __restrict__ dst,
                                                        unsigned int* __restrict__ bcur,
                                                        unsigned int* __restrict__ staged, int E, int NB) {
    __shared__ unsigned int hist[MAXB], sc[MAXB], lbase[MAXB], gbase[MAXB];
    __shared__ unsigned int stage[EPB];
    __shared__ unsigned short sbuck[EPB];
    int start = blockIdx.x * EPB;
    int cnt = min(EPB, E - start);
    for (int j = threadIdx.x; j < MAXB; j += 256) hist[j] = 0u;
    __syncthreads();

    unsigned int rec[EPT], rnk[EPT], bkt[EPT];
#pragma unroll
    for (int u = 0; u < EPT; ++u) {
        int k = u * 256 + threadIdx.x;
        if (k < cnt) {
            unsigned int d = (unsigned int)dst[start + k];
            unsigned int s = (unsigned int)src[start + k];
            unsigned int b = d >> NPB_SHIFT;
            rec[u] = ((d & (NPB - 1)) << SRC_BITS) | s;
            bkt[u] = b;
            rnk[u] = atomicAdd(&hist[b], 1u);   // in-bucket rank, single pass
        }
    }
    __syncthreads();
    {
        int i0 = threadIdx.x, i1 = threadIdx.x + 256;
        sc[i0] = hist[i0]; sc[i1] = hist[i1];
        __syncthreads();
        for (int o = 1; o < MAXB; o <<= 1) {
            unsigned int v0 = (i0 >= o) ? sc[i0 - o] : 0u;
            unsigned int v1 = (i1 >= o) ? sc[i1 - o] : 0u;
            __syncthreads();
            sc[i0] += v0; sc[i1] += v1;
            __syncthreads();
        }
    }
    for (int j = threadIdx.x; j < MAXB; j += 256) {
        unsigned int c = hist[j];
        lbase[j] = sc[j] - c;
        gbase[j] = (j < NB && c) ? atomicAdd(&bcur[j], c) : 0u;
    }
    __syncthreads();
#pragma unroll
    for (int u = 0; u < EPT; ++u) {
        int k = u * 256 + threadIdx.x;
        if (k < cnt) {
            unsigned int pos = lbase[bkt[u]] + rnk[u];
            stage[pos] = rec[u];
            sbuck[pos] = (unsigned short)bkt[u];
        }
    }
    __syncthreads();
    for (int t = threadIdx.x; t < cnt; t += 256) {
        unsigned int b = sbuck[t];
        staged[(size_t)gbase[b] + (t - lbase[b])] = stage[t];
    }
}

// ---------------- K4: per-bucket exact CSR + off/deg/dinv/ttx ----------------
__global__ __launch_bounds__(256) void build_csr_kernel(const unsigned int* __restrict__ staged,
                                                        const unsigned int* __restrict__ bcur,
                                                        const float* __restrict__ x,
                                                        unsigned int* __restrict__ csr,
                                                        unsigned int* __restrict__ off,
                                                        unsigned int* __restrict__ deg,
                                                        float* __restrict__ dinv,
                                                        float* __restrict__ ttx, int N) {
    __shared__ unsigned int cnt[NPB], loff[NPB], ncur[NPB];
    int b = blockIdx.x;
    unsigned int base = (unsigned int)b * BCAP;
    unsigned int m = bcur[b] - base;
    int node0 = b << NPB_SHIFT;
    cnt[threadIdx.x] = 0u;
    __syncthreads();
    for (unsigned int t = threadIdx.x; t < m; t += 256)
        atomicAdd(&cnt[staged[(size_t)base + t] >> SRC_BITS], 1u);
    __syncthreads();
    unsigned int v = cnt[threadIdx.x];
    loff[threadIdx.x] = v;
    __syncthreads();
    for (int o = 1; o < NPB; o <<= 1) {
        unsigned int a = (threadIdx.x >= (unsigned)o) ? loff[threadIdx.x - o] : 0u;
        __syncthreads();
        loff[threadIdx.x] += a;
        __syncthreads();
    }
    unsigned int ex = loff[threadIdx.x] - v;
    ncur[threadIdx.x] = ex;
    int node = node0 + threadIdx.x;
    if (node < N) {
        off[node] = base + ex;
        deg[node] = v;
        float di = 1.0f / sqrtf((float)(v + 1u));  // +1 self loop
        dinv[node] = di;
        ttx[node] = di * x[node];
    }
    __syncthreads();
    for (unsigned int t = threadIdx.x; t < m; t += 256) {
        unsigned int rec = staged[(size_t)base + t];
        unsigned int p = atomicAdd(&ncur[rec >> SRC_BITS], 1u);
        csr[(size_t)base + p] = rec & SRC_MASK;
    }
}

// ---------------- LUT build (65 blocks); block 0 also inits bcur ----------------
__global__ __launch_bounds__(256) void lut_kernel(const float* __restrict__ W1, const float* __restrict__ b1,
                                                  const float* __restrict__ W2,
                                                  float* __restrict__ Alut, float* __restrict__ Blut,
                                                  float* __restrict__ tvals,
                                                  unsigned int* __restrict__ bcur, int NB) {
    __shared__ float w1[64], bb[64], tv[64];
    __shared__ int rnk[64];
    __shared__ float sW2[64 * 32];
    __shared__ double red[2][256];
    int tid = threadIdx.x;
    if (blockIdx.x == 0) {
        for (int t = tid; t < NB; t += 256) bcur[t] = (unsigned int)t * BCAP;
    }
    if (tid < 64) {
        float w = W1[tid], b = b1[tid];
        w1[tid] = w; bb[tid] = b;
        tv[tid] = (w != 0.f) ? (-b / w) : __uint_as_float(0x7F800000u);  // +inf for degenerate
    }
    for (int t = tid; t < 64 * 32; t += 256) sW2[t] = W2[t];
    __syncthreads();
    if (tid < 64) {
        int r = 0;
        float tj = tv[tid];
        for (int k = 0; k < 64; ++k)
            if (w1[k] != 0.f && (tv[k] < tj || (tv[k] == tj && k < tid))) ++r;
        rnk[tid] = r;
        if (blockIdx.x == 0) tvals[tid] = tv[tid];
    }
    __syncthreads();
    int s = blockIdx.x;                 // segment 0..64
    int c = tid & 31, slice = tid >> 5; // 8 j-slices x 32 channels
    double da = 0.0, db = 0.0;
#pragma unroll
    for (int u = 0; u < 8; ++u) {
        int j = slice * 8 + u;
        float w = w1[j];
        bool act = (w > 0.f) ? (rnk[j] < s) : ((w < 0.f) ? (rnk[j] >= s) : (bb[j] > 0.f));
        if (act) {
            double w2 = (double)sW2[j * 32 + c];
            da += (double)w * w2;
            db += (double)bb[j] * w2;
        }
    }
    red[0][tid] = da; red[1][tid] = db;
    __syncthreads();
    for (int o = 128; o >= 32; o >>= 1) {
        if (tid < o) { red[0][tid] += red[0][tid + o]; red[1][tid] += red[1][tid + o]; }
        __syncthreads();
    }
    if (tid < 32) {
        Alut[s * 32 + tid] = (float)red[0][tid];
        Blut[s * 32 + tid] = (float)red[1][tid];
    }
}

// ---------------- layer-1 gather + fused segment classification -> recs ----------------
__global__ __launch_bounds__(256) void gather1_kernel(const unsigned int* __restrict__ csr,
                                                      const unsigned int* __restrict__ off,
                                                      const unsigned int* __restrict__ deg,
                                                      const float* __restrict__ dinv,
                                                      const float* __restrict__ tt,
                                                      const float* __restrict__ tvals,
                                                      uint4* __restrict__ recs, int N) {
    __shared__ float st[64];
    for (int t = threadIdx.x; t < 64; t += 256) st[t] = tvals[t];
    __syncthreads();
    int tid = blockIdx.x * 256 + threadIdx.x;
    int i = tid >> 2, l = tid & 3;
    if (i >= N) return;
    unsigned int o = off[i], n = deg[i];
    float acc0 = 0.f, acc1 = 0.f;
    unsigned int k = l;
    for (; k + 4 < n; k += 8) { acc0 += tt[csr[o + k]]; acc1 += tt[csr[o + k + 4]]; }
    if (k < n) acc0 += tt[csr[o + k]];
    float acc = acc0 + acc1;
    acc += __shfl_xor(acc, 1, 4);
    acc += __shfl_xor(acc, 2, 4);
    float di = dinv[i];
    float a = di * (acc + tt[i]);        // agg1 (all 4 lanes hold it)
    unsigned int cv = 0;
#pragma unroll
    for (int j = 0; j < 16; ++j) cv += (st[l * 16 + j] < a) ? 1u : 0u;
    cv += __shfl_xor(cv, 1, 4);
    cv += __shfl_xor(cv, 2, 4);
    if (l == 0) recs[i] = make_uint4(__float_as_uint(a * di), __float_as_uint(di), cv, 0u);
}

// ---------------- layer-2 LUT gather + shuffle transform -> SPLIT planes ttA/ttB ----------------
#define G2_ITERS 4
#define FMA4(R, ACC)                                                          \
    {                                                                         \
        float4 A_ = sA2[(R).z * 8 + cc], B_ = sB2[(R).z * 8 + cc];            \
        float p_ = __uint_as_float((R).x), q_ = __uint_as_float((R).y);       \
        (ACC).x = fmaf(A_.x, p_, fmaf(B_.x, q_, (ACC).x));                    \
        (ACC).y = fmaf(A_.y, p_, fmaf(B_.y, q_, (ACC).y));                    \
        (ACC).z = fmaf(A_.z, p_, fmaf(B_.z, q_, (ACC).z));                    \
        (ACC).w = fmaf(A_.w, p_, fmaf(B_.w, q_, (ACC).w));                    \
    }
__global__ __launch_bounds__(256) void gather2t3_kernel(const unsigned int* __restrict__ csr,
                                                        const unsigned int* __restrict__ off,
                                                        const unsigned int* __restrict__ deg,
                                                        const float* __restrict__ dinv,
                                                        const uint4* __restrict__ recs,
                                                        const float* __restrict__ Alut, const float* __restrict__ Blut,
                                                        const float* __restrict__ b2, const float* __restrict__ W3,
                                                        float* __restrict__ ttA, float* __restrict__ ttB, int N) {
    __shared__ float4 sA2[65 * 8], sB2[65 * 8];
    __shared__ float2 sW3p[32 * 8];
    __shared__ float sb2[32];
    for (int t = threadIdx.x; t < 65 * 8; t += 256) {
        int s = t >> 3, q = t & 7;
        sA2[t] = make_float4(Alut[s * 32 + q], Alut[s * 32 + q + 8],
                             Alut[s * 32 + q + 16], Alut[s * 32 + q + 24]);
        sB2[t] = make_float4(Blut[s * 32 + q], Blut[s * 32 + q + 8],
                             Blut[s * 32 + q + 16], Blut[s * 32 + q + 24]);
    }
    for (int t = threadIdx.x; t < 32 * 8; t += 256) {
        int k = t >> 3, q = t & 7;
        sW3p[t] = make_float2(W3[k * 16 + q], W3[k * 16 + q + 8]);
    }
    if (threadIdx.x < 32) sb2[threadIdx.x] = b2[threadIdx.x];
    __syncthreads();

    int g = threadIdx.x >> 3, cc = threadIdx.x & 7;
    for (int iter = 0; iter < G2_ITERS; ++iter) {
        int d = blockIdx.x * (32 * G2_ITERS) + iter * 32 + g;
        if (d >= N) continue;
        float dd = dinv[d];
        unsigned int o = off[d], n = deg[d];
        uint4 rs = recs[d];
        float ps = __uint_as_float(rs.x), qs = __uint_as_float(rs.y);
        float4 As = sA2[rs.z * 8 + cc], Bs = sB2[rs.z * 8 + cc];
        float4 aP, aQ;
        aP.x = fmaf(As.x, ps, Bs.x * qs); aP.y = fmaf(As.y, ps, Bs.y * qs);
        aP.z = fmaf(As.z, ps, Bs.z * qs); aP.w = fmaf(As.w, ps, Bs.w * qs);
        aQ = make_float4(0.f, 0.f, 0.f, 0.f);
        unsigned int P = n >> 1;
        if (P >= 2) {
            unsigned int c0 = csr[o], c1 = csr[o + 1];
            unsigned int c2 = csr[o + 2], c3 = csr[o + 3];
            uint4 r0 = recs[c0], r1 = recs[c1];
            for (unsigned int j = 0; j + 2 < P; ++j) {
                unsigned int base = o + 2 * j;
                unsigned int nc0 = csr[base + 4], nc1 = csr[base + 5];
                uint4 nr0 = recs[c2], nr1 = recs[c3];
                FMA4(r0, aP); FMA4(r1, aQ);
                r0 = nr0; r1 = nr1; c2 = nc0; c3 = nc1;
            }
            uint4 m0 = recs[c2], m1 = recs[c3];
            FMA4(r0, aP); FMA4(r1, aQ);
            FMA4(m0, aP); FMA4(m1, aQ);
        } else if (P == 1) {
            uint4 r0 = recs[csr[o]], r1 = recs[csr[o + 1]];
            FMA4(r0, aP); FMA4(r1, aQ);
        }
        if (n & 1u) {
            uint4 r0 = recs[csr[o + n - 1]];
            FMA4(r0, aP);
        }
        float hv0 = fmaxf(fmaf(dd, aP.x + aQ.x, sb2[cc]), 0.f);
        float hv1 = fmaxf(fmaf(dd, aP.y + aQ.y, sb2[cc + 8]), 0.f);
        float hv2 = fmaxf(fmaf(dd, aP.z + aQ.z, sb2[cc + 16]), 0.f);
        float hv3 = fmaxf(fmaf(dd, aP.w + aQ.w, sb2[cc + 24]), 0.f);

        float t0 = 0.f, t1 = 0.f;
#pragma unroll
        for (int l2 = 0; l2 < 8; ++l2) {
            float hk = __shfl(hv0, l2, 8);
            float2 w = sW3p[l2 * 8 + cc];
            t0 = fmaf(hk, w.x, t0); t1 = fmaf(hk, w.y, t1);
        }
#pragma unroll
        for (int l2 = 0; l2 < 8; ++l2) {
            float hk = __shfl(hv1, l2, 8);
            float2 w = sW3p[(8 + l2) * 8 + cc];
            t0 = fmaf(hk, w.x, t0); t1 = fmaf(hk, w.y, t1);
        }
#pragma unroll
        for (int l2 = 0; l2 < 8; ++l2) {
            float hk = __shfl(hv2, l2, 8);
            float2 w = sW3p[(16 + l2) * 8 + cc];
            t0 = fmaf(hk, w.x, t0); t1 = fmaf(hk, w.y, t1);
        }
#pragma unroll
        for (int l2 = 0; l2 < 8; ++l2) {
            float hk = __shfl(hv3, l2, 8);
            float2 w = sW3p[(24 + l2) * 8 + cc];
            t0 = fmaf(hk, w.x, t0); t1 = fmaf(hk, w.y, t1);
        }
        ttA[(size_t)d * 8 + cc] = dd * t0;   // channels 0..7  (plane A, 3.2MB)
        ttB[(size_t)d * 8 + cc] = dd * t1;   // channels 8..15 (plane B, 3.2MB)
    }
}

// ---------------- layer-3 gather over ONE 3.2MB plane (L2-resident) ----------------
// 2 lanes/node; lane reads float4 (l) of the 32B plane row; csr one pair ahead.
template<int HALF>
__global__ __launch_bounds__(256) void gather3t4_half_kernel(const unsigned int* __restrict__ csr,
                                                             const unsigned int* __restrict__ off,
                                                             const unsigned int* __restrict__ deg,
                                                             const float* __restrict__ dinv,
                                                             const float* __restrict__ plane,
                                                             const float* __restrict__ b3, const float* __restrict__ W4,
                                                             float* __restrict__ partial,
                                                             float* __restrict__ tt4, int N) {
    int tid = blockIdx.x * 256 + threadIdx.x;
    int d = tid >> 1, l = tid & 1;
    if (d >= N) return;
    float dd = dinv[d];
    unsigned int o = off[d], n = deg[d];
    const float4* p4 = reinterpret_cast<const float4*>(plane);   // row = 2 float4
    float4 acc = p4[(size_t)d * 2 + l];   // self term
    float4 acc1 = make_float4(0.f, 0.f, 0.f, 0.f);
    unsigned int k = 0;
    if (n >= 2) {
        unsigned int s0 = csr[o], s1 = csr[o + 1];
        k = 2;
        for (; k + 1 < n; k += 2) {
            unsigned int t0 = csr[o + k], t1 = csr[o + k + 1];   // csr 1 pair ahead
            float4 v0 = p4[(size_t)s0 * 2 + l];
            float4 v1 = p4[(size_t)s1 * 2 + l];
            acc.x += v0.x; acc.y += v0.y; acc.z += v0.z; acc.w += v0.w;
            acc1.x += v1.x; acc1.y += v1.y; acc1.z += v1.z; acc1.w += v1.w;
            s0 = t0; s1 = t1;
        }
        {
            float4 v0 = p4[(size_t)s0 * 2 + l];
            float4 v1 = p4[(size_t)s1 * 2 + l];
            acc.x += v0.x; acc.y += v0.y; acc.z += v0.z; acc.w += v0.w;
            acc1.x += v1.x; acc1.y += v1.y; acc1.z += v1.z; acc1.w += v1.w;
        }
    }
    if (k < n) {
        float4 v0 = p4[(size_t)csr[o + k] * 2 + l];
        acc.x += v0.x; acc.y += v0.y; acc.z += v0.z; acc.w += v0.w;
    }
    acc.x += acc1.x; acc.y += acc1.y; acc.z += acc1.z; acc.w += acc1.w;
    const int fi = 2 * HALF + l;          // channel quad 0..3
    float4 b3v = reinterpret_cast<const float4*>(b3)[fi];
    float4 w4v = reinterpret_cast<const float4*>(W4)[fi];
    float v = fmaxf(fmaf(dd, acc.x, b3v.x), 0.f) * w4v.x;
    v = fmaf(fmaxf(fmaf(dd, acc.y, b3v.y), 0.f), w4v.y, v);
    v = fmaf(fmaxf(fmaf(dd, acc.z, b3v.z), 0.f), w4v.z, v);
    v = fmaf(fmaxf(fmaf(dd, acc.w, b3v.w), 0.f), w4v.w, v);
    v += __shfl_xor(v, 1, 2);
    if (l == 0) {
        if (HALF == 0) partial[d] = v;
        else           tt4[d] = dd * (partial[d] + v);
    }
}

// ---------------- layer-4 scalar gather -> out ----------------
__global__ void gather4_kernel(const unsigned int* __restrict__ csr, const unsigned int* __restrict__ off,
                               const unsigned int* __restrict__ deg, const float* __restrict__ dinv,
                               const float* __restrict__ tt, const float* __restrict__ b4,
                               float* __restrict__ out, int N) {
    int tid = blockIdx.x * blockDim.x + threadIdx.x;
    int i = tid >> 2, l = tid & 3;
    if (i >= N) return;
    unsigned int o = off[i], n = deg[i];
    float acc0 = 0.f, acc1 = 0.f;
    unsigned int k = l;
    for (; k + 4 < n; k += 8) { acc0 += tt[csr[o + k]]; acc1 += tt[csr[o + k + 4]]; }
    if (k < n) acc0 += tt[csr[o + k]];
    float acc = acc0 + acc1;
    acc += __shfl_xor(acc, 1, 4);
    acc += __shfl_xor(acc, 2, 4);
    if (l == 0) out[i] = dinv[i] * (acc + tt[i]) + b4[0];
}

extern "C" void kernel_launch(void* const* d_in, const int* in_sizes, int n_in,
                              void* d_out, int out_size, void* d_ws, size_t ws_size,
                              hipStream_t stream) {
    const float* x  = (const float*)d_in[0];
    const int* eidx = (const int*)d_in[1];
    const float* W1 = (const float*)d_in[2];
    const float* b1 = (const float*)d_in[3];
    const float* W2 = (const float*)d_in[4];
    const float* b2 = (const float*)d_in[5];
    const float* W3 = (const float*)d_in[6];
    const float* b3 = (const float*)d_in[7];
    const float* W4 = (const float*)d_in[8];
    const float* b4 = (const float*)d_in[9];
    float* out = (float*)d_out;

    const int N = in_sizes[0];         // 100000
    const int E = in_sizes[1] / 2;     // 3200000
    const int* src = eidx;
    const int* dst = eidx + E;
    const int NB = (N + NPB - 1) >> NPB_SHIFT;   // 391 buckets

    char* ws = (char*)d_ws;
    unsigned int* bcur  = (unsigned int*)ws;  ws += MAXB * 4;
    float* tvals = (float*)ws;                ws += 64 * 4;
    float* Alut  = (float*)ws;                ws += 65 * 32 * 4;
    float* Blut  = (float*)ws;                ws += 65 * 32 * 4;
    unsigned int* off = (unsigned int*)ws;    ws += (size_t)N * 4;
    unsigned int* deg = (unsigned int*)ws;    ws += (size_t)N * 4;
    float* dinv = (float*)ws;                 ws += (size_t)N * 4;
    float* ttx  = (float*)ws;                 ws += (size_t)N * 4;
    float* tt4  = (float*)ws;                 ws += (size_t)N * 4;
    float* part = (float*)ws;                 ws += (size_t)N * 4;
    uint4* recs = (uint4*)ws;                 ws += (size_t)N * 16;
    unsigned int* csr = (unsigned int*)ws;    ws += (size_t)NB * BCAP * 4;   // padded CSR (14.4MB)
    unsigned int* staged = (unsigned int*)ws; // padded staged (14.4MB); planes alias it
    float* ttA = (float*)staged;              // plane A: N*8 floats (3.2MB)
    float* ttB = ttA + (size_t)N * 8;         // plane B: N*8 floats (3.2MB)

    const int nPartBlocks = (E + EPB - 1) / EPB;   // 782

    lut_kernel<<<65, 256, 0, stream>>>(W1, b1, W2, Alut, Blut, tvals, bcur, NB);
    partition_kernel<<<nPartBlocks, 256, 0, stream>>>(src, dst, bcur, staged, E, NB);
    build_csr_kernel<<<NB, 256, 0, stream>>>(staged, bcur, x, csr, off, deg, dinv, ttx, N);

    gather1_kernel<<<((size_t)N * 4 + 255) / 256, 256, 0, stream>>>(csr, off, deg, dinv, ttx, tvals, recs, N);
    gather2t3_kernel<<<(N + 32 * G2_ITERS - 1) / (32 * G2_ITERS), 256, 0, stream>>>(csr, off, deg, dinv, recs, Alut, Blut, b2, W3, ttA, ttB, N);
    gather3t4_half_kernel<0><<<((size_t)N * 2 + 255) / 256, 256, 0, stream>>>(csr, off, deg, dinv, ttA, b3, W4, part, tt4, N);
    gather3t4_half_kernel<1><<<((size_t)N * 2 + 255) / 256, 256, 0, stream>>>(csr, off, deg, dinv, ttB, b3, W4, part, tt4, N);
    gather4_kernel<<<((size_t)N * 4 + 255) / 256, 256, 0, stream>>>(csr, off, deg, dinv, tt4, b4, out, N);
}

// Round 19
// 183.872 us; speedup vs baseline: 1.3235x; 1.1843x over previous
//
#include <hip/hip_runtime.h>

#define NPB_SHIFT 8
#define NPB 256          // nodes per bucket
#define EPB 4096         // edges per partition block (782 blocks, 32KB LDS)
#define EPT 16           // edges per thread in partition (EPB/256)
#define MAXB 512         // padded bucket count (NB = ceil(100000/256) = 391)
#define BCAP 9216        // fixed bucket capacity: E/NB=8184, sigma~90 -> +11 sigma
#define SRC_BITS 17      // N=100000 < 2^17
#define SRC_MASK 0x1FFFFu

// ---------------- K3: single-pass LDS-staged partition (register-held ranks) ----------------
__global__ __launch_bounds__(256) void partition_kernel(const int* __restrict__ src,
                                                        const int* __restrict__ dst,
                                                        unsigned int* __restrict__ bcur,
                                                        unsigned int* __restrict__ staged, int E, int NB) {
    __shared__ unsigned int hist[MAXB], sc[MAXB], lbase[MAXB], gbase[MAXB];
    __shared__ unsigned int stage[EPB];
    __shared__ unsigned short sbuck[EPB];
    int start = blockIdx.x * EPB;
    int cnt = min(EPB, E - start);
    for (int j = threadIdx.x; j < MAXB; j += 256) hist[j] = 0u;
    __syncthreads();

    unsigned int rec[EPT], rnk[EPT], bkt[EPT];
#pragma unroll
    for (int u = 0; u < EPT; ++u) {
        int k = u * 256 + threadIdx.x;
        if (k < cnt) {
            unsigned int d = (unsigned int)dst[start + k];
            unsigned int s = (unsigned int)src[start + k];
            unsigned int b = d >> NPB_SHIFT;
            rec[u] = ((d & (NPB - 1)) << SRC_BITS) | s;
            bkt[u] = b;
            rnk[u] = atomicAdd(&hist[b], 1u);   // in-bucket rank, single pass
        }
    }
    __syncthreads();
    {
        int i0 = threadIdx.x, i1 = threadIdx.x + 256;
        sc[i0] = hist[i0]; sc[i1] = hist[i1];
        __syncthreads();
        for (int o = 1; o < MAXB; o <<= 1) {
            unsigned int v0 = (i0 >= o) ? sc[i0 - o] : 0u;
            unsigned int v1 = (i1 >= o) ? sc[i1 - o] : 0u;
            __syncthreads();
            sc[i0] += v0; sc[i1] += v1;
            __syncthreads();
        }
    }
    for (int j = threadIdx.x; j < MAXB; j += 256) {
        unsigned int c = hist[j];
        lbase[j] = sc[j] - c;
        gbase[j] = (j < NB && c) ? atomicAdd(&bcur[j], c) : 0u;
    }
    __syncthreads();
#pragma unroll
    for (int u = 0; u < EPT; ++u) {
        int k = u * 256 + threadIdx.x;
        if (k < cnt) {
            unsigned int pos = lbase[bkt[u]] + rnk[u];
            stage[pos] = rec[u];
            sbuck[pos] = (unsigned short)bkt[u];
        }
    }
    __syncthreads();
    for (int t = threadIdx.x; t < cnt; t += 256) {
        unsigned int b = sbuck[t];
        staged[(size_t)gbase[b] + (t - lbase[b])] = stage[t];
    }
}

// ---------------- K4: per-bucket exact CSR + off/deg/dinv/ttx ----------------
__global__ __launch_bounds__(256) void build_csr_kernel(const unsigned int* __restrict__ staged,
                                                        const unsigned int* __restrict__ bcur,
                                                        const float* __restrict__ x,
                                                        unsigned int* __restrict__ csr,
                                                        unsigned int* __restrict__ off,
                                                        unsigned int* __restrict__ deg,
                                                        float* __restrict__ dinv,
                                                        float* __restrict__ ttx, int N) {
    __shared__ unsigned int cnt[NPB], loff[NPB], ncur[NPB];
    int b = blockIdx.x;
    unsigned int base = (unsigned int)b * BCAP;
    unsigned int m = bcur[b] - base;
    int node0 = b << NPB_SHIFT;
    cnt[threadIdx.x] = 0u;
    __syncthreads();
    for (unsigned int t = threadIdx.x; t < m; t += 256)
        atomicAdd(&cnt[staged[(size_t)base + t] >> SRC_BITS], 1u);
    __syncthreads();
    unsigned int v = cnt[threadIdx.x];
    loff[threadIdx.x] = v;
    __syncthreads();
    for (int o = 1; o < NPB; o <<= 1) {
        unsigned int a = (threadIdx.x >= (unsigned)o) ? loff[threadIdx.x - o] : 0u;
        __syncthreads();
        loff[threadIdx.x] += a;
        __syncthreads();
    }
    unsigned int ex = loff[threadIdx.x] - v;
    ncur[threadIdx.x] = ex;
    int node = node0 + threadIdx.x;
    if (node < N) {
        off[node] = base + ex;
        deg[node] = v;
        float di = 1.0f / sqrtf((float)(v + 1u));  // +1 self loop
        dinv[node] = di;
        ttx[node] = di * x[node];
    }
    __syncthreads();
    for (unsigned int t = threadIdx.x; t < m; t += 256) {
        unsigned int rec = staged[(size_t)base + t];
        unsigned int p = atomicAdd(&ncur[rec >> SRC_BITS], 1u);
        csr[(size_t)base + p] = rec & SRC_MASK;
    }
}

// ---------------- LUT build (65 blocks); block 0 also inits bcur ----------------
__global__ __launch_bounds__(256) void lut_kernel(const float* __restrict__ W1, const float* __restrict__ b1,
                                                  const float* __restrict__ W2,
                                                  float* __restrict__ Alut, float* __restrict__ Blut,
                                                  float* __restrict__ tvals,
                                                  unsigned int* __restrict__ bcur, int NB) {
    __shared__ float w1[64], bb[64], tv[64];
    __shared__ int rnk[64];
    __shared__ float sW2[64 * 32];
    __shared__ double red[2][256];
    int tid = threadIdx.x;
    if (blockIdx.x == 0) {
        for (int t = tid; t < NB; t += 256) bcur[t] = (unsigned int)t * BCAP;
    }
    if (tid < 64) {
        float w = W1[tid], b = b1[tid];
        w1[tid] = w; bb[tid] = b;
        tv[tid] = (w != 0.f) ? (-b / w) : __uint_as_float(0x7F800000u);  // +inf for degenerate
    }
    for (int t = tid; t < 64 * 32; t += 256) sW2[t] = W2[t];
    __syncthreads();
    if (tid < 64) {
        int r = 0;
        float tj = tv[tid];
        for (int k = 0; k < 64; ++k)
            if (w1[k] != 0.f && (tv[k] < tj || (tv[k] == tj && k < tid))) ++r;
        rnk[tid] = r;
        if (blockIdx.x == 0) tvals[tid] = tv[tid];
    }
    __syncthreads();
    int s = blockIdx.x;                 // segment 0..64
    int c = tid & 31, slice = tid >> 5; // 8 j-slices x 32 channels
    double da = 0.0, db = 0.0;
#pragma unroll
    for (int u = 0; u < 8; ++u) {
        int j = slice * 8 + u;
        float w = w1[j];
        bool act = (w > 0.f) ? (rnk[j] < s) : ((w < 0.f) ? (rnk[j] >= s) : (bb[j] > 0.f));
        if (act) {
            double w2 = (double)sW2[j * 32 + c];
            da += (double)w * w2;
            db += (double)bb[j] * w2;
        }
    }
    red[0][tid] = da; red[1][tid] = db;
    __syncthreads();
    for (int o = 128; o >= 32; o >>= 1) {
        if (tid < o) { red[0][tid] += red[0][tid + o]; red[1][tid] += red[1][tid + o]; }
        __syncthreads();
    }
    if (tid < 32) {
        Alut[s * 32 + tid] = (float)red[0][tid];
        Blut[s * 32 + tid] = (float)red[1][tid];
    }
}

// ---------------- layer-1 gather + fused segment classification -> recs ----------------
__global__ __launch_bounds__(256) void gather1_kernel(const unsigned int* __restrict__ csr,
                                                      const unsigned int* __restrict__ off,
                                                      const unsigned int* __restrict__ deg,
                                                      const float* __restrict__ dinv,
                                                      const float* __restrict__ tt,
                                                      const float* __restrict__ tvals,
                                                      uint4* __restrict__ recs, int N) {
    __shared__ float st[64];
    for (int t = threadIdx.x; t < 64; t += 256) st[t] = tvals[t];
    __syncthreads();
    int tid = blockIdx.x * 256 + threadIdx.x;
    int i = tid >> 2, l = tid & 3;
    if (i >= N) return;
    unsigned int o = off[i], n = deg[i];
    float acc0 = 0.f, acc1 = 0.f;
    unsigned int k = l;
    for (; k + 4 < n; k += 8) { acc0 += tt[csr[o + k]]; acc1 += tt[csr[o + k + 4]]; }
    if (k < n) acc0 += tt[csr[o + k]];
    float acc = acc0 + acc1;
    acc += __shfl_xor(acc, 1, 4);
    acc += __shfl_xor(acc, 2, 4);
    float di = dinv[i];
    float a = di * (acc + tt[i]);        // agg1 (all 4 lanes hold it)
    unsigned int cv = 0;
#pragma unroll
    for (int j = 0; j < 16; ++j) cv += (st[l * 16 + j] < a) ? 1u : 0u;
    cv += __shfl_xor(cv, 1, 4);
    cv += __shfl_xor(cv, 2, 4);
    if (l == 0) recs[i] = make_uint4(__float_as_uint(a * di), __float_as_uint(di), cv, 0u);
}

// ---------------- layer-2 LUT gather + in-register shuffle transform -> tt3 ----------------
// 8 lanes/node; LUT stride padded to 9 float4s (bank = (z*36+cc*4)%32 varies with z -> no
// structural 8-way conflict); G2_ITERS=2 -> 1563 blocks (~6/CU) for occupancy.
#define G2_ITERS 2
#define LSTRIDE 9
#define FMA4(R, ACC)                                                          \
    {                                                                         \
        float4 A_ = sA2[(R).z * LSTRIDE + cc], B_ = sB2[(R).z * LSTRIDE + cc];\
        float p_ = __uint_as_float((R).x), q_ = __uint_as_float((R).y);       \
        (ACC).x = fmaf(A_.x, p_, fmaf(B_.x, q_, (ACC).x));                    \
        (ACC).y = fmaf(A_.y, p_, fmaf(B_.y, q_, (ACC).y));                    \
        (ACC).z = fmaf(A_.z, p_, fmaf(B_.z, q_, (ACC).z));                    \
        (ACC).w = fmaf(A_.w, p_, fmaf(B_.w, q_, (ACC).w));                    \
    }
__global__ __launch_bounds__(256) void gather2t3_kernel(const unsigned int* __restrict__ csr,
                                                        const unsigned int* __restrict__ off,
                                                        const unsigned int* __restrict__ deg,
                                                        const float* __restrict__ dinv,
                                                        const uint4* __restrict__ recs,
                                                        const float* __restrict__ Alut, const float* __restrict__ Blut,
                                                        const float* __restrict__ b2, const float* __restrict__ W3,
                                                        float* __restrict__ tt3, int N) {
    __shared__ float4 sA2[65 * LSTRIDE], sB2[65 * LSTRIDE];
    __shared__ float2 sW3p[32 * 8];
    __shared__ float sb2[32];
    for (int t = threadIdx.x; t < 65 * 8; t += 256) {
        int s = t >> 3, q = t & 7;
        sA2[s * LSTRIDE + q] = make_float4(Alut[s * 32 + q], Alut[s * 32 + q + 8],
                                           Alut[s * 32 + q + 16], Alut[s * 32 + q + 24]);
        sB2[s * LSTRIDE + q] = make_float4(Blut[s * 32 + q], Blut[s * 32 + q + 8],
                                           Blut[s * 32 + q + 16], Blut[s * 32 + q + 24]);
    }
    for (int t = threadIdx.x; t < 32 * 8; t += 256) {
        int k = t >> 3, q = t & 7;
        sW3p[t] = make_float2(W3[k * 16 + q], W3[k * 16 + q + 8]);
    }
    if (threadIdx.x < 32) sb2[threadIdx.x] = b2[threadIdx.x];
    __syncthreads();

    int g = threadIdx.x >> 3, cc = threadIdx.x & 7;
    for (int iter = 0; iter < G2_ITERS; ++iter) {
        int d = blockIdx.x * (32 * G2_ITERS) + iter * 32 + g;
        if (d >= N) continue;
        float dd = dinv[d];
        unsigned int o = off[d], n = deg[d];
        uint4 rs = recs[d];
        float ps = __uint_as_float(rs.x), qs = __uint_as_float(rs.y);
        float4 As = sA2[rs.z * LSTRIDE + cc], Bs = sB2[rs.z * LSTRIDE + cc];
        float4 aP, aQ;
        aP.x = fmaf(As.x, ps, Bs.x * qs); aP.y = fmaf(As.y, ps, Bs.y * qs);
        aP.z = fmaf(As.z, ps, Bs.z * qs); aP.w = fmaf(As.w, ps, Bs.w * qs);
        aQ = make_float4(0.f, 0.f, 0.f, 0.f);
        unsigned int P = n >> 1;
        if (P >= 2) {
            unsigned int c0 = csr[o], c1 = csr[o + 1];
            unsigned int c2 = csr[o + 2], c3 = csr[o + 3];
            uint4 r0 = recs[c0], r1 = recs[c1];
            for (unsigned int j = 0; j + 2 < P; ++j) {
                unsigned int base = o + 2 * j;
                unsigned int nc0 = csr[base + 4], nc1 = csr[base + 5];  // csr pair j+2
                uint4 nr0 = recs[c2], nr1 = recs[c3];                   // recs pair j+1
                FMA4(r0, aP); FMA4(r1, aQ);                             // FMA pair j
                r0 = nr0; r1 = nr1; c2 = nc0; c3 = nc1;
            }
            uint4 m0 = recs[c2], m1 = recs[c3];
            FMA4(r0, aP); FMA4(r1, aQ);
            FMA4(m0, aP); FMA4(m1, aQ);
        } else if (P == 1) {
            uint4 r0 = recs[csr[o]], r1 = recs[csr[o + 1]];
            FMA4(r0, aP); FMA4(r1, aQ);
        }
        if (n & 1u) {
            uint4 r0 = recs[csr[o + n - 1]];
            FMA4(r0, aP);
        }
        float hv0 = fmaxf(fmaf(dd, aP.x + aQ.x, sb2[cc]), 0.f);
        float hv1 = fmaxf(fmaf(dd, aP.y + aQ.y, sb2[cc + 8]), 0.f);
        float hv2 = fmaxf(fmaf(dd, aP.z + aQ.z, sb2[cc + 16]), 0.f);
        float hv3 = fmaxf(fmaf(dd, aP.w + aQ.w, sb2[cc + 24]), 0.f);

        // in-register W3 transform: t3[c] = sum_k h2[k]*W3[k][c], c in {cc, cc+8}
        float t0 = 0.f, t1 = 0.f;
#pragma unroll
        for (int l2 = 0; l2 < 8; ++l2) {
            float hk = __shfl(hv0, l2, 8);
            float2 w = sW3p[l2 * 8 + cc];
            t0 = fmaf(hk, w.x, t0); t1 = fmaf(hk, w.y, t1);
        }
#pragma unroll
        for (int l2 = 0; l2 < 8; ++l2) {
            float hk = __shfl(hv1, l2, 8);
            float2 w = sW3p[(8 + l2) * 8 + cc];
            t0 = fmaf(hk, w.x, t0); t1 = fmaf(hk, w.y, t1);
        }
#pragma unroll
        for (int l2 = 0; l2 < 8; ++l2) {
            float hk = __shfl(hv2, l2, 8);
            float2 w = sW3p[(16 + l2) * 8 + cc];
            t0 = fmaf(hk, w.x, t0); t1 = fmaf(hk, w.y, t1);
        }
#pragma unroll
        for (int l2 = 0; l2 < 8; ++l2) {
            float hk = __shfl(hv3, l2, 8);
            float2 w = sW3p[(24 + l2) * 8 + cc];
            t0 = fmaf(hk, w.x, t0); t1 = fmaf(hk, w.y, t1);
        }
        tt3[(size_t)d * 16 + cc] = dd * t0;
        tt3[(size_t)d * 16 + cc + 8] = dd * t1;
    }
}

// ---------------- layer-3 gather (float4, 4 lanes/node, csr 1-quad ahead) -> tt4 ----------------
__global__ __launch_bounds__(256) void gather3t4_kernel(const unsigned int* __restrict__ csr,
                                                        const unsigned int* __restrict__ off,
                                                        const unsigned int* __restrict__ deg,
                                                        const float* __restrict__ dinv,
                                                        const float* __restrict__ tt3,
                                                        const float* __restrict__ b3, const float* __restrict__ W4,
                                                        float* __restrict__ tt4, int N) {
    int tid = blockIdx.x * 256 + threadIdx.x;
    int d = tid >> 2, l = tid & 3;
    if (d >= N) return;
    float dd = dinv[d];
    unsigned int o = off[d], n = deg[d];
    const float4* t34 = reinterpret_cast<const float4*>(tt3);
    float4 acc = t34[(size_t)d * 4 + l];   // self term
    float4 acc1 = make_float4(0.f, 0.f, 0.f, 0.f);
    unsigned int k = 0;
    if (n >= 4) {
        unsigned int s0 = csr[o], s1 = csr[o + 1], s2 = csr[o + 2], s3 = csr[o + 3];
        k = 4;
        for (; k + 3 < n; k += 4) {
            unsigned int t0 = csr[o + k], t1 = csr[o + k + 1], t2 = csr[o + k + 2], t3 = csr[o + k + 3];
            float4 v0 = t34[(size_t)s0 * 4 + l];
            float4 v1 = t34[(size_t)s1 * 4 + l];
            float4 v2 = t34[(size_t)s2 * 4 + l];
            float4 v3 = t34[(size_t)s3 * 4 + l];
            acc.x += v0.x + v2.x; acc.y += v0.y + v2.y; acc.z += v0.z + v2.z; acc.w += v0.w + v2.w;
            acc1.x += v1.x + v3.x; acc1.y += v1.y + v3.y; acc1.z += v1.z + v3.z; acc1.w += v1.w + v3.w;
            s0 = t0; s1 = t1; s2 = t2; s3 = t3;
        }
        {   // drain in-flight quad
            float4 v0 = t34[(size_t)s0 * 4 + l];
            float4 v1 = t34[(size_t)s1 * 4 + l];
            float4 v2 = t34[(size_t)s2 * 4 + l];
            float4 v3 = t34[(size_t)s3 * 4 + l];
            acc.x += v0.x + v2.x; acc.y += v0.y + v2.y; acc.z += v0.z + v2.z; acc.w += v0.w + v2.w;
            acc1.x += v1.x + v3.x; acc1.y += v1.y + v3.y; acc1.z += v1.z + v3.z; acc1.w += v1.w + v3.w;
        }
    }
    for (; k < n; ++k) {
        float4 v0 = t34[(size_t)csr[o + k] * 4 + l];
        acc.x += v0.x; acc.y += v0.y; acc.z += v0.z; acc.w += v0.w;
    }
    acc.x += acc1.x; acc.y += acc1.y; acc.z += acc1.z; acc.w += acc1.w;
    float4 b3v = reinterpret_cast<const float4*>(b3)[l];
    float4 w4v = reinterpret_cast<const float4*>(W4)[l];
    float v = fmaxf(fmaf(dd, acc.x, b3v.x), 0.f) * w4v.x;
    v = fmaf(fmaxf(fmaf(dd, acc.y, b3v.y), 0.f), w4v.y, v);
    v = fmaf(fmaxf(fmaf(dd, acc.z, b3v.z), 0.f), w4v.z, v);
    v = fmaf(fmaxf(fmaf(dd, acc.w, b3v.w), 0.f), w4v.w, v);
    v += __shfl_xor(v, 1, 4);
    v += __shfl_xor(v, 2, 4);
    if (l == 0) tt4[d] = dd * v;
}

// ---------------- layer-4 scalar gather -> out ----------------
__global__ void gather4_kernel(const unsigned int* __restrict__ csr, const unsigned int* __restrict__ off,
                               const unsigned int* __restrict__ deg, const float* __restrict__ dinv,
                               const float* __restrict__ tt, const float* __restrict__ b4,
                               float* __restrict__ out, int N) {
    int tid = blockIdx.x * blockDim.x + threadIdx.x;
    int i = tid >> 2, l = tid & 3;
    if (i >= N) return;
    unsigned int o = off[i], n = deg[i];
    float acc0 = 0.f, acc1 = 0.f;
    unsigned int k = l;
    for (; k + 4 < n; k += 8) { acc0 += tt[csr[o + k]]; acc1 += tt[csr[o + k + 4]]; }
    if (k < n) acc0 += tt[csr[o + k]];
    float acc = acc0 + acc1;
    acc += __shfl_xor(acc, 1, 4);
    acc += __shfl_xor(acc, 2, 4);
    if (l == 0) out[i] = dinv[i] * (acc + tt[i]) + b4[0];
}

extern "C" void kernel_launch(void* const* d_in, const int* in_sizes, int n_in,
                              void* d_out, int out_size, void* d_ws, size_t ws_size,
                              hipStream_t stream) {
    const float* x  = (const float*)d_in[0];
    const int* eidx = (const int*)d_in[1];
    const float* W1 = (const float*)d_in[2];
    const float* b1 = (const float*)d_in[3];
    const float* W2 = (const float*)d_in[4];
    const float* b2 = (const float*)d_in[5];
    const float* W3 = (const float*)d_in[6];
    const float* b3 = (const float*)d_in[7];
    const float* W4 = (const float*)d_in[8];
    const float* b4 = (const float*)d_in[9];
    float* out = (float*)d_out;

    const int N = in_sizes[0];         // 100000
    const int E = in_sizes[1] / 2;     // 3200000
    const int* src = eidx;
    const int* dst = eidx + E;
    const int NB = (N + NPB - 1) >> NPB_SHIFT;   // 391 buckets

    char* ws = (char*)d_ws;
    unsigned int* bcur  = (unsigned int*)ws;  ws += MAXB * 4;
    float* tvals = (float*)ws;                ws += 64 * 4;
    float* Alut  = (float*)ws;                ws += 65 * 32 * 4;
    float* Blut  = (float*)ws;                ws += 65 * 32 * 4;
    unsigned int* off = (unsigned int*)ws;    ws += (size_t)N * 4;
    unsigned int* deg = (unsigned int*)ws;    ws += (size_t)N * 4;
    float* dinv = (float*)ws;                 ws += (size_t)N * 4;
    float* ttx  = (float*)ws;                 ws += (size_t)N * 4;
    float* tt4  = (float*)ws;                 ws += (size_t)N * 4;
    uint4* recs = (uint4*)ws;                 ws += (size_t)N * 16;
    unsigned int* csr = (unsigned int*)ws;    ws += (size_t)NB * BCAP * 4;   // padded CSR (14.4MB)
    unsigned int* staged = (unsigned int*)ws; // padded staged; tt3 (6.4MB) aliases it
    float* tt3 = (float*)staged;              // staged dead after build_csr

    const int nPartBlocks = (E + EPB - 1) / EPB;   // 782

    lut_kernel<<<65, 256, 0, stream>>>(W1, b1, W2, Alut, Blut, tvals, bcur, NB);
    partition_kernel<<<nPartBlocks, 256, 0, stream>>>(src, dst, bcur, staged, E, NB);
    build_csr_kernel<<<NB, 256, 0, stream>>>(staged, bcur, x, csr, off, deg, dinv, ttx, N);

    gather1_kernel<<<((size_t)N * 4 + 255) / 256, 256, 0, stream>>>(csr, off, deg, dinv, ttx, tvals, recs, N);
    gather2t3_kernel<<<(N + 32 * G2_ITERS - 1) / (32 * G2_ITERS), 256, 0, stream>>>(csr, off, deg, dinv, recs, Alut, Blut, b2, W3, tt3, N);
    gather3t4_kernel<<<((size_t)N * 4 + 255) / 256, 256, 0, stream>>>(csr, off, deg, dinv, tt3, b3, W4, tt4, N);
    gather4_kernel<<<((size_t)N * 4 + 255) / 256, 256, 0, stream>>>(csr, off, deg, dinv, tt4, b4, out, N);
}

// Round 20
// 181.381 us; speedup vs baseline: 1.3417x; 1.0137x over previous
//
#include <hip/hip_runtime.h>

#define NPB_SHIFT 8
#define NPB 256          // nodes per bucket
#define EPB 4096         // edges per partition block (782 blocks, 32KB LDS)
#define EPT 16           // edges per thread in partition (EPB/256)
#define MAXB 512         // padded bucket count (NB = ceil(100000/256) = 391)
#define BCAP 9216        // fixed bucket capacity: E/NB=8184, sigma~90 -> +11 sigma
#define SRC_BITS 17      // N=100000 < 2^17
#define SRC_MASK 0x1FFFFu

// ---------------- K3: single-pass LDS-staged partition (register-held ranks) ----------------
__global__ __launch_bounds__(256) void partition_kernel(const int* __restrict__ src,
                                                        const int* __restrict__ dst,
                                                        unsigned int* __restrict__ bcur,
                                                        unsigned int* __restrict__ staged, int E, int NB) {
    __shared__ unsigned int hist[MAXB], sc[MAXB], lbase[MAXB], gbase[MAXB];
    __shared__ unsigned int stage[EPB];
    __shared__ unsigned short sbuck[EPB];
    int start = blockIdx.x * EPB;
    int cnt = min(EPB, E - start);
    for (int j = threadIdx.x; j < MAXB; j += 256) hist[j] = 0u;
    __syncthreads();

    unsigned int rec[EPT], rnk[EPT], bkt[EPT];
#pragma unroll
    for (int u = 0; u < EPT; ++u) {
        int k = u * 256 + threadIdx.x;
        if (k < cnt) {
            unsigned int d = (unsigned int)dst[start + k];
            unsigned int s = (unsigned int)src[start + k];
            unsigned int b = d >> NPB_SHIFT;
            rec[u] = ((d & (NPB - 1)) << SRC_BITS) | s;
            bkt[u] = b;
            rnk[u] = atomicAdd(&hist[b], 1u);   // in-bucket rank, single pass
        }
    }
    __syncthreads();
    {
        int i0 = threadIdx.x, i1 = threadIdx.x + 256;
        sc[i0] = hist[i0]; sc[i1] = hist[i1];
        __syncthreads();
        for (int o = 1; o < MAXB; o <<= 1) {
            unsigned int v0 = (i0 >= o) ? sc[i0 - o] : 0u;
            unsigned int v1 = (i1 >= o) ? sc[i1 - o] : 0u;
            __syncthreads();
            sc[i0] += v0; sc[i1] += v1;
            __syncthreads();
        }
    }
    for (int j = threadIdx.x; j < MAXB; j += 256) {
        unsigned int c = hist[j];
        lbase[j] = sc[j] - c;
        gbase[j] = (j < NB && c) ? atomicAdd(&bcur[j], c) : 0u;
    }
    __syncthreads();
#pragma unroll
    for (int u = 0; u < EPT; ++u) {
        int k = u * 256 + threadIdx.x;
        if (k < cnt) {
            unsigned int pos = lbase[bkt[u]] + rnk[u];
            stage[pos] = rec[u];
            sbuck[pos] = (unsigned short)bkt[u];
        }
    }
    __syncthreads();
    for (int t = threadIdx.x; t < cnt; t += 256) {
        unsigned int b = sbuck[t];
        staged[(size_t)gbase[b] + (t - lbase[b])] = stage[t];
    }
}

// ---------------- K4: per-bucket exact CSR + off/deg/dinv/ttx ----------------
__global__ __launch_bounds__(256) void build_csr_kernel(const unsigned int* __restrict__ staged,
                                                        const unsigned int* __restrict__ bcur,
                                                        const float* __restrict__ x,
                                                        unsigned int* __restrict__ csr,
                                                        unsigned int* __restrict__ off,
                                                        unsigned int* __restrict__ deg,
                                                        float* __restrict__ dinv,
                                                        float* __restrict__ ttx, int N) {
    __shared__ unsigned int cnt[NPB], loff[NPB], ncur[NPB];
    int b = blockIdx.x;
    unsigned int base = (unsigned int)b * BCAP;
    unsigned int m = bcur[b] - base;
    int node0 = b << NPB_SHIFT;
    cnt[threadIdx.x] = 0u;
    __syncthreads();
    for (unsigned int t = threadIdx.x; t < m; t += 256)
        atomicAdd(&cnt[staged[(size_t)base + t] >> SRC_BITS], 1u);
    __syncthreads();
    unsigned int v = cnt[threadIdx.x];
    loff[threadIdx.x] = v;
    __syncthreads();
    for (int o = 1; o < NPB; o <<= 1) {
        unsigned int a = (threadIdx.x >= (unsigned)o) ? loff[threadIdx.x - o] : 0u;
        __syncthreads();
        loff[threadIdx.x] += a;
        __syncthreads();
    }
    unsigned int ex = loff[threadIdx.x] - v;
    ncur[threadIdx.x] = ex;
    int node = node0 + threadIdx.x;
    if (node < N) {
        off[node] = base + ex;
        deg[node] = v;
        float di = 1.0f / sqrtf((float)(v + 1u));  // +1 self loop
        dinv[node] = di;
        ttx[node] = di * x[node];
    }
    __syncthreads();
    for (unsigned int t = threadIdx.x; t < m; t += 256) {
        unsigned int rec = staged[(size_t)base + t];
        unsigned int p = atomicAdd(&ncur[rec >> SRC_BITS], 1u);
        csr[(size_t)base + p] = rec & SRC_MASK;
    }
}

// ---------------- LUT build (65 blocks); block 0 also inits bcur ----------------
__global__ __launch_bounds__(256) void lut_kernel(const float* __restrict__ W1, const float* __restrict__ b1,
                                                  const float* __restrict__ W2,
                                                  float* __restrict__ Alut, float* __restrict__ Blut,
                                                  float* __restrict__ tvals,
                                                  unsigned int* __restrict__ bcur, int NB) {
    __shared__ float w1[64], bb[64], tv[64];
    __shared__ int rnk[64];
    __shared__ float sW2[64 * 32];
    __shared__ double red[2][256];
    int tid = threadIdx.x;
    if (blockIdx.x == 0) {
        for (int t = tid; t < NB; t += 256) bcur[t] = (unsigned int)t * BCAP;
    }
    if (tid < 64) {
        float w = W1[tid], b = b1[tid];
        w1[tid] = w; bb[tid] = b;
        tv[tid] = (w != 0.f) ? (-b / w) : __uint_as_float(0x7F800000u);  // +inf for degenerate
    }
    for (int t = tid; t < 64 * 32; t += 256) sW2[t] = W2[t];
    __syncthreads();
    if (tid < 64) {
        int r = 0;
        float tj = tv[tid];
        for (int k = 0; k < 64; ++k)
            if (w1[k] != 0.f && (tv[k] < tj || (tv[k] == tj && k < tid))) ++r;
        rnk[tid] = r;
        if (blockIdx.x == 0) tvals[tid] = tv[tid];
    }
    __syncthreads();
    int s = blockIdx.x;                 // segment 0..64
    int c = tid & 31, slice = tid >> 5; // 8 j-slices x 32 channels
    double da = 0.0, db = 0.0;
#pragma unroll
    for (int u = 0; u < 8; ++u) {
        int j = slice * 8 + u;
        float w = w1[j];
        bool act = (w > 0.f) ? (rnk[j] < s) : ((w < 0.f) ? (rnk[j] >= s) : (bb[j] > 0.f));
        if (act) {
            double w2 = (double)sW2[j * 32 + c];
            da += (double)w * w2;
            db += (double)bb[j] * w2;
        }
    }
    red[0][tid] = da; red[1][tid] = db;
    __syncthreads();
    for (int o = 128; o >= 32; o >>= 1) {
        if (tid < o) { red[0][tid] += red[0][tid + o]; red[1][tid] += red[1][tid + o]; }
        __syncthreads();
    }
    if (tid < 32) {
        Alut[s * 32 + tid] = (float)red[0][tid];
        Blut[s * 32 + tid] = (float)red[1][tid];
    }
}

// ---------------- layer-1 gather + fused segment classification -> recs ----------------
__global__ __launch_bounds__(256) void gather1_kernel(const unsigned int* __restrict__ csr,
                                                      const unsigned int* __restrict__ off,
                                                      const unsigned int* __restrict__ deg,
                                                      const float* __restrict__ dinv,
                                                      const float* __restrict__ tt,
                                                      const float* __restrict__ tvals,
                                                      uint4* __restrict__ recs, int N) {
    __shared__ float st[64];
    for (int t = threadIdx.x; t < 64; t += 256) st[t] = tvals[t];
    __syncthreads();
    int tid = blockIdx.x * 256 + threadIdx.x;
    int i = tid >> 2, l = tid & 3;
    if (i >= N) return;
    unsigned int o = off[i], n = deg[i];
    float acc0 = 0.f, acc1 = 0.f;
    unsigned int k = l;
    // 2-stage pipeline: csr index one step ahead of tt load
    if (k < n) {
        unsigned int c0 = csr[o + k];
        unsigned int k2 = k + 4;
        for (; k2 < n; k2 += 4) {
            unsigned int c1 = csr[o + k2];
            float v = tt[c0];
            if ((k2 - l) & 4u) acc1 += v; else acc0 += v;
            c0 = c1;
        }
        float v = tt[c0];
        if ((k2 - l) & 4u) acc1 += v; else acc0 += v;
    }
    float acc = acc0 + acc1;
    acc += __shfl_xor(acc, 1, 4);
    acc += __shfl_xor(acc, 2, 4);
    float di = dinv[i];
    float a = di * (acc + tt[i]);        // agg1 (all 4 lanes hold it)
    unsigned int cv = 0;
#pragma unroll
    for (int j = 0; j < 16; ++j) cv += (st[l * 16 + j] < a) ? 1u : 0u;
    cv += __shfl_xor(cv, 1, 4);
    cv += __shfl_xor(cv, 2, 4);
    if (l == 0) recs[i] = make_uint4(__float_as_uint(a * di), __float_as_uint(di), cv, 0u);
}

// ---------------- layer-2 LUT gather + in-register shuffle transform -> tt3 ----------------
#define G2_ITERS 2
#define LSTRIDE 9
#define FMA4(R, ACC)                                                          \
    {                                                                         \
        float4 A_ = sA2[(R).z * LSTRIDE + cc], B_ = sB2[(R).z * LSTRIDE + cc];\
        float p_ = __uint_as_float((R).x), q_ = __uint_as_float((R).y);       \
        (ACC).x = fmaf(A_.x, p_, fmaf(B_.x, q_, (ACC).x));                    \
        (ACC).y = fmaf(A_.y, p_, fmaf(B_.y, q_, (ACC).y));                    \
        (ACC).z = fmaf(A_.z, p_, fmaf(B_.z, q_, (ACC).z));                    \
        (ACC).w = fmaf(A_.w, p_, fmaf(B_.w, q_, (ACC).w));                    \
    }
__global__ __launch_bounds__(256) void gather2t3_kernel(const unsigned int* __restrict__ csr,
                                                        const unsigned int* __restrict__ off,
                                                        const unsigned int* __restrict__ deg,
                                                        const float* __restrict__ dinv,
                                                        const uint4* __restrict__ recs,
                                                        const float* __restrict__ Alut, const float* __restrict__ Blut,
                                                        const float* __restrict__ b2, const float* __restrict__ W3,
                                                        float* __restrict__ tt3, int N) {
    __shared__ float4 sA2[65 * LSTRIDE], sB2[65 * LSTRIDE];
    __shared__ float2 sW3p[32 * 8];
    __shared__ float sb2[32];
    for (int t = threadIdx.x; t < 65 * 8; t += 256) {
        int s = t >> 3, q = t & 7;
        sA2[s * LSTRIDE + q] = make_float4(Alut[s * 32 + q], Alut[s * 32 + q + 8],
                                           Alut[s * 32 + q + 16], Alut[s * 32 + q + 24]);
        sB2[s * LSTRIDE + q] = make_float4(Blut[s * 32 + q], Blut[s * 32 + q + 8],
                                           Blut[s * 32 + q + 16], Blut[s * 32 + q + 24]);
    }
    for (int t = threadIdx.x; t < 32 * 8; t += 256) {
        int k = t >> 3, q = t & 7;
        sW3p[t] = make_float2(W3[k * 16 + q], W3[k * 16 + q + 8]);
    }
    if (threadIdx.x < 32) sb2[threadIdx.x] = b2[threadIdx.x];
    __syncthreads();

    int g = threadIdx.x >> 3, cc = threadIdx.x & 7;
    for (int iter = 0; iter < G2_ITERS; ++iter) {
        int d = blockIdx.x * (32 * G2_ITERS) + iter * 32 + g;
        if (d >= N) continue;
        float dd = dinv[d];
        unsigned int o = off[d], n = deg[d];
        uint4 rs = recs[d];
        float ps = __uint_as_float(rs.x), qs = __uint_as_float(rs.y);
        float4 As = sA2[rs.z * LSTRIDE + cc], Bs = sB2[rs.z * LSTRIDE + cc];
        float4 aP, aQ;
        aP.x = fmaf(As.x, ps, Bs.x * qs); aP.y = fmaf(As.y, ps, Bs.y * qs);
        aP.z = fmaf(As.z, ps, Bs.z * qs); aP.w = fmaf(As.w, ps, Bs.w * qs);
        aQ = make_float4(0.f, 0.f, 0.f, 0.f);
        unsigned int P = n >> 1;
        if (P >= 2) {
            unsigned int c0 = csr[o], c1 = csr[o + 1];
            unsigned int c2 = csr[o + 2], c3 = csr[o + 3];
            uint4 r0 = recs[c0], r1 = recs[c1];
            for (unsigned int j = 0; j + 2 < P; ++j) {
                unsigned int base = o + 2 * j;
                unsigned int nc0 = csr[base + 4], nc1 = csr[base + 5];  // csr pair j+2
                uint4 nr0 = recs[c2], nr1 = recs[c3];                   // recs pair j+1
                FMA4(r0, aP); FMA4(r1, aQ);                             // FMA pair j
                r0 = nr0; r1 = nr1; c2 = nc0; c3 = nc1;
            }
            uint4 m0 = recs[c2], m1 = recs[c3];
            FMA4(r0, aP); FMA4(r1, aQ);
            FMA4(m0, aP); FMA4(m1, aQ);
        } else if (P == 1) {
            uint4 r0 = recs[csr[o]], r1 = recs[csr[o + 1]];
            FMA4(r0, aP); FMA4(r1, aQ);
        }
        if (n & 1u) {
            uint4 r0 = recs[csr[o + n - 1]];
            FMA4(r0, aP);
        }
        float hv0 = fmaxf(fmaf(dd, aP.x + aQ.x, sb2[cc]), 0.f);
        float hv1 = fmaxf(fmaf(dd, aP.y + aQ.y, sb2[cc + 8]), 0.f);
        float hv2 = fmaxf(fmaf(dd, aP.z + aQ.z, sb2[cc + 16]), 0.f);
        float hv3 = fmaxf(fmaf(dd, aP.w + aQ.w, sb2[cc + 24]), 0.f);

        float t0 = 0.f, t1 = 0.f;
#pragma unroll
        for (int l2 = 0; l2 < 8; ++l2) {
            float hk = __shfl(hv0, l2, 8);
            float2 w = sW3p[l2 * 8 + cc];
            t0 = fmaf(hk, w.x, t0); t1 = fmaf(hk, w.y, t1);
        }
#pragma unroll
        for (int l2 = 0; l2 < 8; ++l2) {
            float hk = __shfl(hv1, l2, 8);
            float2 w = sW3p[(8 + l2) * 8 + cc];
            t0 = fmaf(hk, w.x, t0); t1 = fmaf(hk, w.y, t1);
        }
#pragma unroll
        for (int l2 = 0; l2 < 8; ++l2) {
            float hk = __shfl(hv2, l2, 8);
            float2 w = sW3p[(16 + l2) * 8 + cc];
            t0 = fmaf(hk, w.x, t0); t1 = fmaf(hk, w.y, t1);
        }
#pragma unroll
        for (int l2 = 0; l2 < 8; ++l2) {
            float hk = __shfl(hv3, l2, 8);
            float2 w = sW3p[(24 + l2) * 8 + cc];
            t0 = fmaf(hk, w.x, t0); t1 = fmaf(hk, w.y, t1);
        }
        tt3[(size_t)d * 16 + cc] = dd * t0;
        tt3[(size_t)d * 16 + cc + 8] = dd * t1;
    }
}

// ---------------- layer-3 gather: 2-STAGE rotating quad pipeline -> tt4 ----------------
// 4 lanes/node. Per iter: issue csr(quad j+2) and rows(quad j+1), FMA quad j.
__global__ __launch_bounds__(256) void gather3t4_kernel(const unsigned int* __restrict__ csr,
                                                        const unsigned int* __restrict__ off,
                                                        const unsigned int* __restrict__ deg,
                                                        const float* __restrict__ dinv,
                                                        const float* __restrict__ tt3,
                                                        const float* __restrict__ b3, const float* __restrict__ W4,
                                                        float* __restrict__ tt4, int N) {
    int tid = blockIdx.x * 256 + threadIdx.x;
    int d = tid >> 2, l = tid & 3;
    if (d >= N) return;
    float dd = dinv[d];
    unsigned int o = off[d], n = deg[d];
    const float4* t34 = reinterpret_cast<const float4*>(tt3);
    float4 acc = t34[(size_t)d * 4 + l];   // self term
    float4 acc1 = make_float4(0.f, 0.f, 0.f, 0.f);
    unsigned int Q = n >> 2;               // full quads
    unsigned int k = Q << 2;
    if (Q >= 2) {
        // prologue: csr quad0, rows quad0, csr quad1
        unsigned int a0 = csr[o], a1 = csr[o + 1], a2 = csr[o + 2], a3 = csr[o + 3];
        unsigned int b0 = csr[o + 4], b1 = csr[o + 5], b2 = csr[o + 6], b3i = csr[o + 7];
        float4 v0 = t34[(size_t)a0 * 4 + l];
        float4 v1 = t34[(size_t)a1 * 4 + l];
        float4 v2 = t34[(size_t)a2 * 4 + l];
        float4 v3 = t34[(size_t)a3 * 4 + l];
        for (unsigned int j = 0; j + 2 < Q; ++j) {
            unsigned int base = o + 4 * j;
            unsigned int nb0 = csr[base + 8], nb1 = csr[base + 9];     // csr quad j+2
            unsigned int nb2 = csr[base + 10], nb3 = csr[base + 11];
            float4 w0 = t34[(size_t)b0 * 4 + l];                       // rows quad j+1
            float4 w1 = t34[(size_t)b1 * 4 + l];
            float4 w2 = t34[(size_t)b2 * 4 + l];
            float4 w3 = t34[(size_t)b3i * 4 + l];
            acc.x += v0.x + v2.x; acc.y += v0.y + v2.y; acc.z += v0.z + v2.z; acc.w += v0.w + v2.w;
            acc1.x += v1.x + v3.x; acc1.y += v1.y + v3.y; acc1.z += v1.z + v3.z; acc1.w += v1.w + v3.w;
            v0 = w0; v1 = w1; v2 = w2; v3 = w3;
            b0 = nb0; b1 = nb1; b2 = nb2; b3i = nb3;
        }
        // epilogue: FMA quad Q-2 (in v), then rows+FMA quad Q-1 (csr in b)
        float4 w0 = t34[(size_t)b0 * 4 + l];
        float4 w1 = t34[(size_t)b1 * 4 + l];
        float4 w2 = t34[(size_t)b2 * 4 + l];
        float4 w3 = t34[(size_t)b3i * 4 + l];
        acc.x += v0.x + v2.x; acc.y += v0.y + v2.y; acc.z += v0.z + v2.z; acc.w += v0.w + v2.w;
        acc1.x += v1.x + v3.x; acc1.y += v1.y + v3.y; acc1.z += v1.z + v3.z; acc1.w += v1.w + v3.w;
        acc.x += w0.x + w2.x; acc.y += w0.y + w2.y; acc.z += w0.z + w2.z; acc.w += w0.w + w2.w;
        acc1.x += w1.x + w3.x; acc1.y += w1.y + w3.y; acc1.z += w1.z + w3.z; acc1.w += w1.w + w3.w;
    } else if (Q == 1) {
        unsigned int a0 = csr[o], a1 = csr[o + 1], a2 = csr[o + 2], a3 = csr[o + 3];
        float4 v0 = t34[(size_t)a0 * 4 + l];
        float4 v1 = t34[(size_t)a1 * 4 + l];
        float4 v2 = t34[(size_t)a2 * 4 + l];
        float4 v3 = t34[(size_t)a3 * 4 + l];
        acc.x += v0.x + v2.x; acc.y += v0.y + v2.y; acc.z += v0.z + v2.z; acc.w += v0.w + v2.w;
        acc1.x += v1.x + v3.x; acc1.y += v1.y + v3.y; acc1.z += v1.z + v3.z; acc1.w += v1.w + v3.w;
    }
    for (; k < n; ++k) {
        float4 v0 = t34[(size_t)csr[o + k] * 4 + l];
        acc.x += v0.x; acc.y += v0.y; acc.z += v0.z; acc.w += v0.w;
    }
    acc.x += acc1.x; acc.y += acc1.y; acc.z += acc1.z; acc.w += acc1.w;
    float4 b3v = reinterpret_cast<const float4*>(b3)[l];
    float4 w4v = reinterpret_cast<const float4*>(W4)[l];
    float v = fmaxf(fmaf(dd, acc.x, b3v.x), 0.f) * w4v.x;
    v = fmaf(fmaxf(fmaf(dd, acc.y, b3v.y), 0.f), w4v.y, v);
    v = fmaf(fmaxf(fmaf(dd, acc.z, b3v.z), 0.f), w4v.z, v);
    v = fmaf(fmaxf(fmaf(dd, acc.w, b3v.w), 0.f), w4v.w, v);
    v += __shfl_xor(v, 1, 4);
    v += __shfl_xor(v, 2, 4);
    if (l == 0) tt4[d] = dd * v;
}

// ---------------- layer-4 scalar gather (2-stage pipeline) -> out ----------------
__global__ void gather4_kernel(const unsigned int* __restrict__ csr, const unsigned int* __restrict__ off,
                               const unsigned int* __restrict__ deg, const float* __restrict__ dinv,
                               const float* __restrict__ tt, const float* __restrict__ b4,
                               float* __restrict__ out, int N) {
    int tid = blockIdx.x * blockDim.x + threadIdx.x;
    int i = tid >> 2, l = tid & 3;
    if (i >= N) return;
    unsigned int o = off[i], n = deg[i];
    float acc0 = 0.f, acc1 = 0.f;
    unsigned int k = l;
    if (k < n) {
        unsigned int c0 = csr[o + k];
        unsigned int k2 = k + 4;
        for (; k2 < n; k2 += 4) {
            unsigned int c1 = csr[o + k2];
            float v = tt[c0];
            if ((k2 - l) & 4u) acc1 += v; else acc0 += v;
            c0 = c1;
        }
        float v = tt[c0];
        if ((k2 - l) & 4u) acc1 += v; else acc0 += v;
    }
    float acc = acc0 + acc1;
    acc += __shfl_xor(acc, 1, 4);
    acc += __shfl_xor(acc, 2, 4);
    if (l == 0) out[i] = dinv[i] * (acc + tt[i]) + b4[0];
}

extern "C" void kernel_launch(void* const* d_in, const int* in_sizes, int n_in,
                              void* d_out, int out_size, void* d_ws, size_t ws_size,
                              hipStream_t stream) {
    const float* x  = (const float*)d_in[0];
    const int* eidx = (const int*)d_in[1];
    const float* W1 = (const float*)d_in[2];
    const float* b1 = (const float*)d_in[3];
    const float* W2 = (const float*)d_in[4];
    const float* b2 = (const float*)d_in[5];
    const float* W3 = (const float*)d_in[6];
    const float* b3 = (const float*)d_in[7];
    const float* W4 = (const float*)d_in[8];
    const float* b4 = (const float*)d_in[9];
    float* out = (float*)d_out;

    const int N = in_sizes[0];         // 100000
    const int E = in_sizes[1] / 2;     // 3200000
    const int* src = eidx;
    const int* dst = eidx + E;
    const int NB = (N + NPB - 1) >> NPB_SHIFT;   // 391 buckets

    char* ws = (char*)d_ws;
    unsigned int* bcur  = (unsigned int*)ws;  ws += MAXB * 4;
    float* tvals = (float*)ws;                ws += 64 * 4;
    float* Alut  = (float*)ws;                ws += 65 * 32 * 4;
    float* Blut  = (float*)ws;                ws += 65 * 32 * 4;
    unsigned int* off = (unsigned int*)ws;    ws += (size_t)N * 4;
    unsigned int* deg = (unsigned int*)ws;    ws += (size_t)N * 4;
    float* dinv = (float*)ws;                 ws += (size_t)N * 4;
    float* ttx  = (float*)ws;                 ws += (size_t)N * 4;
    float* tt4  = (float*)ws;                 ws += (size_t)N * 4;
    uint4* recs = (uint4*)ws;                 ws += (size_t)N * 16;
    unsigned int* csr = (unsigned int*)ws;    ws += (size_t)NB * BCAP * 4;   // padded CSR (14.4MB)
    unsigned int* staged = (unsigned int*)ws; // padded staged; tt3 (6.4MB) aliases it
    float* tt3 = (float*)staged;              // staged dead after build_csr

    const int nPartBlocks = (E + EPB - 1) / EPB;   // 782

    lut_kernel<<<65, 256, 0, stream>>>(W1, b1, W2, Alut, Blut, tvals, bcur, NB);
    partition_kernel<<<nPartBlocks, 256, 0, stream>>>(src, dst, bcur, staged, E, NB);
    build_csr_kernel<<<NB, 256, 0, stream>>>(staged, bcur, x, csr, off, deg, dinv, ttx, N);

    gather1_kernel<<<((size_t)N * 4 + 255) / 256, 256, 0, stream>>>(csr, off, deg, dinv, ttx, tvals, recs, N);
    gather2t3_kernel<<<(N + 32 * G2_ITERS - 1) / (32 * G2_ITERS), 256, 0, stream>>>(csr, off, deg, dinv, recs, Alut, Blut, b2, W3, tt3, N);
    gather3t4_kernel<<<((size_t)N * 4 + 255) / 256, 256, 0, stream>>>(csr, off, deg, dinv, tt3, b3, W4, tt4, N);
    gather4_kernel<<<((size_t)N * 4 + 255) / 256, 256, 0, stream>>>(csr, off, deg, dinv, tt4, b4, out, N);
}

// Round 21
// 179.941 us; speedup vs baseline: 1.3524x; 1.0080x over previous
//
#include <hip/hip_runtime.h>

#define NPB_SHIFT 8
#define NPB 256          // nodes per bucket
#define EPB 4096         // edges per partition block (782 blocks, 32KB LDS)
#define EPT 16           // edges per thread in partition (EPB/256)
#define MAXB 512         // padded bucket count (NB = ceil(100000/256) = 391)
#define BCAP 9216        // fixed bucket capacity: E/NB=8184, sigma~90 -> +11 sigma
#define SRC_BITS 17      // N=100000 < 2^17
#define SRC_MASK 0x1FFFFu

// ---------------- K3: single-pass LDS-staged partition (register-held ranks) ----------------
__global__ __launch_bounds__(256) void partition_kernel(const int* __restrict__ src,
                                                        const int* __restrict__ dst,
                                                        unsigned int* __restrict__ bcur,
                                                        unsigned int* __restrict__ staged, int E, int NB) {
    __shared__ unsigned int hist[MAXB], sc[MAXB], lbase[MAXB], gbase[MAXB];
    __shared__ unsigned int stage[EPB];
    __shared__ unsigned short sbuck[EPB];
    int start = blockIdx.x * EPB;
    int cnt = min(EPB, E - start);
    for (int j = threadIdx.x; j < MAXB; j += 256) hist[j] = 0u;
    __syncthreads();

    unsigned int rec[EPT], rnk[EPT], bkt[EPT];
#pragma unroll
    for (int u = 0; u < EPT; ++u) {
        int k = u * 256 + threadIdx.x;
        if (k < cnt) {
            unsigned int d = (unsigned int)dst[start + k];
            unsigned int s = (unsigned int)src[start + k];
            unsigned int b = d >> NPB_SHIFT;
            rec[u] = ((d & (NPB - 1)) << SRC_BITS) | s;
            bkt[u] = b;
            rnk[u] = atomicAdd(&hist[b], 1u);   // in-bucket rank, single pass
        }
    }
    __syncthreads();
    {
        int i0 = threadIdx.x, i1 = threadIdx.x + 256;
        sc[i0] = hist[i0]; sc[i1] = hist[i1];
        __syncthreads();
        for (int o = 1; o < MAXB; o <<= 1) {
            unsigned int v0 = (i0 >= o) ? sc[i0 - o] : 0u;
            unsigned int v1 = (i1 >= o) ? sc[i1 - o] : 0u;
            __syncthreads();
            sc[i0] += v0; sc[i1] += v1;
            __syncthreads();
        }
    }
    for (int j = threadIdx.x; j < MAXB; j += 256) {
        unsigned int c = hist[j];
        lbase[j] = sc[j] - c;
        gbase[j] = (j < NB && c) ? atomicAdd(&bcur[j], c) : 0u;
    }
    __syncthreads();
#pragma unroll
    for (int u = 0; u < EPT; ++u) {
        int k = u * 256 + threadIdx.x;
        if (k < cnt) {
            unsigned int pos = lbase[bkt[u]] + rnk[u];
            stage[pos] = rec[u];
            sbuck[pos] = (unsigned short)bkt[u];
        }
    }
    __syncthreads();
    for (int t = threadIdx.x; t < cnt; t += 256) {
        unsigned int b = sbuck[t];
        staged[(size_t)gbase[b] + (t - lbase[b])] = stage[t];
    }
}

// ---------------- K4: per-bucket exact CSR + off/deg/dinv/ttx ----------------
__global__ __launch_bounds__(256) void build_csr_kernel(const unsigned int* __restrict__ staged,
                                                        const unsigned int* __restrict__ bcur,
                                                        const float* __restrict__ x,
                                                        unsigned int* __restrict__ csr,
                                                        unsigned int* __restrict__ off,
                                                        unsigned int* __restrict__ deg,
                                                        float* __restrict__ dinv,
                                                        float* __restrict__ ttx, int N) {
    __shared__ unsigned int cnt[NPB], loff[NPB], ncur[NPB];
    int b = blockIdx.x;
    unsigned int base = (unsigned int)b * BCAP;
    unsigned int m = bcur[b] - base;
    int node0 = b << NPB_SHIFT;
    cnt[threadIdx.x] = 0u;
    __syncthreads();
    for (unsigned int t = threadIdx.x; t < m; t += 256)
        atomicAdd(&cnt[staged[(size_t)base + t] >> SRC_BITS], 1u);
    __syncthreads();
    unsigned int v = cnt[threadIdx.x];
    loff[threadIdx.x] = v;
    __syncthreads();
    for (int o = 1; o < NPB; o <<= 1) {
        unsigned int a = (threadIdx.x >= (unsigned)o) ? loff[threadIdx.x - o] : 0u;
        __syncthreads();
        loff[threadIdx.x] += a;
        __syncthreads();
    }
    unsigned int ex = loff[threadIdx.x] - v;
    ncur[threadIdx.x] = ex;
    int node = node0 + threadIdx.x;
    if (node < N) {
        off[node] = base + ex;
        deg[node] = v;
        float di = 1.0f / sqrtf((float)(v + 1u));  // +1 self loop
        dinv[node] = di;
        ttx[node] = di * x[node];
    }
    __syncthreads();
    for (unsigned int t = threadIdx.x; t < m; t += 256) {
        unsigned int rec = staged[(size_t)base + t];
        unsigned int p = atomicAdd(&ncur[rec >> SRC_BITS], 1u);
        csr[(size_t)base + p] = rec & SRC_MASK;
    }
}

// ---------------- LUT build (65 blocks); block 0 also inits bcur ----------------
__global__ __launch_bounds__(256) void lut_kernel(const float* __restrict__ W1, const float* __restrict__ b1,
                                                  const float* __restrict__ W2,
                                                  float* __restrict__ Alut, float* __restrict__ Blut,
                                                  float* __restrict__ tvals,
                                                  unsigned int* __restrict__ bcur, int NB) {
    __shared__ float w1[64], bb[64], tv[64];
    __shared__ int rnk[64];
    __shared__ float sW2[64 * 32];
    __shared__ double red[2][256];
    int tid = threadIdx.x;
    if (blockIdx.x == 0) {
        for (int t = tid; t < NB; t += 256) bcur[t] = (unsigned int)t * BCAP;
    }
    if (tid < 64) {
        float w = W1[tid], b = b1[tid];
        w1[tid] = w; bb[tid] = b;
        tv[tid] = (w != 0.f) ? (-b / w) : __uint_as_float(0x7F800000u);  // +inf for degenerate
    }
    for (int t = tid; t < 64 * 32; t += 256) sW2[t] = W2[t];
    __syncthreads();
    if (tid < 64) {
        int r = 0;
        float tj = tv[tid];
        for (int k = 0; k < 64; ++k)
            if (w1[k] != 0.f && (tv[k] < tj || (tv[k] == tj && k < tid))) ++r;
        rnk[tid] = r;
        if (blockIdx.x == 0) tvals[tid] = tv[tid];
    }
    __syncthreads();
    int s = blockIdx.x;                 // segment 0..64
    int c = tid & 31, slice = tid >> 5; // 8 j-slices x 32 channels
    double da = 0.0, db = 0.0;
#pragma unroll
    for (int u = 0; u < 8; ++u) {
        int j = slice * 8 + u;
        float w = w1[j];
        bool act = (w > 0.f) ? (rnk[j] < s) : ((w < 0.f) ? (rnk[j] >= s) : (bb[j] > 0.f));
        if (act) {
            double w2 = (double)sW2[j * 32 + c];
            da += (double)w * w2;
            db += (double)bb[j] * w2;
        }
    }
    red[0][tid] = da; red[1][tid] = db;
    __syncthreads();
    for (int o = 128; o >= 32; o >>= 1) {
        if (tid < o) { red[0][tid] += red[0][tid + o]; red[1][tid] += red[1][tid + o]; }
        __syncthreads();
    }
    if (tid < 32) {
        Alut[s * 32 + tid] = (float)red[0][tid];
        Blut[s * 32 + tid] = (float)red[1][tid];
    }
}

// ---------------- layer-1 gather + fused segment classification -> recs ----------------
__global__ __launch_bounds__(256) void gather1_kernel(const unsigned int* __restrict__ csr,
                                                      const unsigned int* __restrict__ off,
                                                      const unsigned int* __restrict__ deg,
                                                      const float* __restrict__ dinv,
                                                      const float* __restrict__ tt,
                                                      const float* __restrict__ tvals,
                                                      uint4* __restrict__ recs, int N) {
    __shared__ float st[64];
    for (int t = threadIdx.x; t < 64; t += 256) st[t] = tvals[t];
    __syncthreads();
    int tid = blockIdx.x * 256 + threadIdx.x;
    int i = tid >> 2, l = tid & 3;
    if (i >= N) return;
    unsigned int o = off[i], n = deg[i];
    float acc0 = 0.f, acc1 = 0.f;
    unsigned int k = l;
    if (k < n) {
        unsigned int c0 = csr[o + k];
        unsigned int k2 = k + 4;
        for (; k2 < n; k2 += 4) {
            unsigned int c1 = csr[o + k2];
            float v = tt[c0];
            if ((k2 - l) & 4u) acc1 += v; else acc0 += v;
            c0 = c1;
        }
        float v = tt[c0];
        if ((k2 - l) & 4u) acc1 += v; else acc0 += v;
    }
    float acc = acc0 + acc1;
    acc += __shfl_xor(acc, 1, 4);
    acc += __shfl_xor(acc, 2, 4);
    float di = dinv[i];
    float a = di * (acc + tt[i]);        // agg1 (all 4 lanes hold it)
    unsigned int cv = 0;
#pragma unroll
    for (int j = 0; j < 16; ++j) cv += (st[l * 16 + j] < a) ? 1u : 0u;
    cv += __shfl_xor(cv, 1, 4);
    cv += __shfl_xor(cv, 2, 4);
    if (l == 0) recs[i] = make_uint4(__float_as_uint(a * di), __float_as_uint(di), cv, 0u);
}

// ---------------- layer-2 LUT gather + in-register shuffle transform -> tt3 ----------------
// 4 lanes/node (lane owns channel-quads cc and cc+4): 16 groups/wave -> 2x streams vs
// 8-lane version. 2-stage rotating pipeline; LUT stride 17 quads (bank-safe).
#define G2_ITERS 2
#define QSTRIDE 17
#define FMA8(R, AC0, AC1)                                                      \
    {                                                                          \
        float4 A0_ = sA2[(R).z * QSTRIDE + cc], A1_ = sA2[(R).z * QSTRIDE + cc + 4]; \
        float4 B0_ = sB2[(R).z * QSTRIDE + cc], B1_ = sB2[(R).z * QSTRIDE + cc + 4]; \
        float p_ = __uint_as_float((R).x), q_ = __uint_as_float((R).y);        \
        (AC0).x = fmaf(A0_.x, p_, fmaf(B0_.x, q_, (AC0).x));                   \
        (AC0).y = fmaf(A0_.y, p_, fmaf(B0_.y, q_, (AC0).y));                   \
        (AC0).z = fmaf(A0_.z, p_, fmaf(B0_.z, q_, (AC0).z));                   \
        (AC0).w = fmaf(A0_.w, p_, fmaf(B0_.w, q_, (AC0).w));                   \
        (AC1).x = fmaf(A1_.x, p_, fmaf(B1_.x, q_, (AC1).x));                   \
        (AC1).y = fmaf(A1_.y, p_, fmaf(B1_.y, q_, (AC1).y));                   \
        (AC1).z = fmaf(A1_.z, p_, fmaf(B1_.z, q_, (AC1).z));                   \
        (AC1).w = fmaf(A1_.w, p_, fmaf(B1_.w, q_, (AC1).w));                   \
    }
__global__ __launch_bounds__(256) void gather2t3_kernel(const unsigned int* __restrict__ csr,
                                                        const unsigned int* __restrict__ off,
                                                        const unsigned int* __restrict__ deg,
                                                        const float* __restrict__ dinv,
                                                        const uint4* __restrict__ recs,
                                                        const float* __restrict__ Alut, const float* __restrict__ Blut,
                                                        const float* __restrict__ b2, const float* __restrict__ W3,
                                                        float* __restrict__ tt3, int N) {
    __shared__ float4 sA2[65 * QSTRIDE], sB2[65 * QSTRIDE];
    __shared__ float4 sW3q[32 * 4];   // [k][output-quad]
    __shared__ float4 sb2q[8];
    for (int t = threadIdx.x; t < 65 * 8; t += 256) {
        int s = t >> 3, q = t & 7;    // channel quad q: channels 4q..4q+3
        sA2[s * QSTRIDE + q] = make_float4(Alut[s * 32 + 4 * q], Alut[s * 32 + 4 * q + 1],
                                           Alut[s * 32 + 4 * q + 2], Alut[s * 32 + 4 * q + 3]);
        sB2[s * QSTRIDE + q] = make_float4(Blut[s * 32 + 4 * q], Blut[s * 32 + 4 * q + 1],
                                           Blut[s * 32 + 4 * q + 2], Blut[s * 32 + 4 * q + 3]);
    }
    for (int t = threadIdx.x; t < 32 * 4; t += 256) {
        int k = t >> 2, oq = t & 3;   // output quad oq: out channels 4oq..4oq+3
        sW3q[t] = make_float4(W3[k * 16 + 4 * oq], W3[k * 16 + 4 * oq + 1],
                              W3[k * 16 + 4 * oq + 2], W3[k * 16 + 4 * oq + 3]);
    }
    if (threadIdx.x < 8) {
        int q = threadIdx.x;
        sb2q[q] = make_float4(b2[4 * q], b2[4 * q + 1], b2[4 * q + 2], b2[4 * q + 3]);
    }
    __syncthreads();

    int g = threadIdx.x >> 2, cc = threadIdx.x & 3;   // 64 groups/block of 4 lanes
    for (int iter = 0; iter < G2_ITERS; ++iter) {
        int d = blockIdx.x * (64 * G2_ITERS) + iter * 64 + g;
        if (d >= N) continue;                 // uniform within the 4-lane group
        float dd = dinv[d];
        unsigned int o = off[d], n = deg[d];
        uint4 rs = recs[d];
        float4 aP0, aP1, aQ0, aQ1;
        {
            float ps = __uint_as_float(rs.x), qs = __uint_as_float(rs.y);
            float4 A0 = sA2[rs.z * QSTRIDE + cc], A1 = sA2[rs.z * QSTRIDE + cc + 4];
            float4 B0 = sB2[rs.z * QSTRIDE + cc], B1 = sB2[rs.z * QSTRIDE + cc + 4];
            aP0.x = fmaf(A0.x, ps, B0.x * qs); aP0.y = fmaf(A0.y, ps, B0.y * qs);
            aP0.z = fmaf(A0.z, ps, B0.z * qs); aP0.w = fmaf(A0.w, ps, B0.w * qs);
            aP1.x = fmaf(A1.x, ps, B1.x * qs); aP1.y = fmaf(A1.y, ps, B1.y * qs);
            aP1.z = fmaf(A1.z, ps, B1.z * qs); aP1.w = fmaf(A1.w, ps, B1.w * qs);
            aQ0 = make_float4(0.f, 0.f, 0.f, 0.f);
            aQ1 = make_float4(0.f, 0.f, 0.f, 0.f);
        }
        unsigned int P = n >> 1;
        if (P >= 2) {
            unsigned int c0 = csr[o], c1 = csr[o + 1];
            unsigned int c2 = csr[o + 2], c3 = csr[o + 3];
            uint4 r0 = recs[c0], r1 = recs[c1];
            for (unsigned int j = 0; j + 2 < P; ++j) {
                unsigned int base = o + 2 * j;
                unsigned int nc0 = csr[base + 4], nc1 = csr[base + 5];  // csr pair j+2
                uint4 nr0 = recs[c2], nr1 = recs[c3];                   // recs pair j+1
                FMA8(r0, aP0, aP1); FMA8(r1, aQ0, aQ1);                 // FMA pair j
                r0 = nr0; r1 = nr1; c2 = nc0; c3 = nc1;
            }
            uint4 m0 = recs[c2], m1 = recs[c3];
            FMA8(r0, aP0, aP1); FMA8(r1, aQ0, aQ1);
            FMA8(m0, aP0, aP1); FMA8(m1, aQ0, aQ1);
        } else if (P == 1) {
            uint4 r0 = recs[csr[o]], r1 = recs[csr[o + 1]];
            FMA8(r0, aP0, aP1); FMA8(r1, aQ0, aQ1);
        }
        if (n & 1u) {
            uint4 r0 = recs[csr[o + n - 1]];
            FMA8(r0, aP0, aP1);
        }
        float4 bA = sb2q[cc], bB = sb2q[cc + 4];
        float4 hA, hB;   // h2 channels 4cc..4cc+3 and 16+4cc..16+4cc+3
        hA.x = fmaxf(fmaf(dd, aP0.x + aQ0.x, bA.x), 0.f);
        hA.y = fmaxf(fmaf(dd, aP0.y + aQ0.y, bA.y), 0.f);
        hA.z = fmaxf(fmaf(dd, aP0.z + aQ0.z, bA.z), 0.f);
        hA.w = fmaxf(fmaf(dd, aP0.w + aQ0.w, bA.w), 0.f);
        hB.x = fmaxf(fmaf(dd, aP1.x + aQ1.x, bB.x), 0.f);
        hB.y = fmaxf(fmaf(dd, aP1.y + aQ1.y, bB.y), 0.f);
        hB.z = fmaxf(fmaf(dd, aP1.z + aQ1.z, bB.z), 0.f);
        hB.w = fmaxf(fmaf(dd, aP1.w + aQ1.w, bB.w), 0.f);

        // W3 transform via 4-lane shuffles: t3 quad cc = sum_k h2[k]*W3[k][4cc..4cc+3]
        float4 t3 = make_float4(0.f, 0.f, 0.f, 0.f);
#define G2_W3STEP(K, HVAL)                                                    \
        {                                                                     \
            float hk = __shfl((HVAL), ((K) >> 2) & 3, 4);                     \
            float4 w = sW3q[(K) * 4 + cc];                                    \
            t3.x = fmaf(hk, w.x, t3.x); t3.y = fmaf(hk, w.y, t3.y);           \
            t3.z = fmaf(hk, w.z, t3.z); t3.w = fmaf(hk, w.w, t3.w);           \
        }
#pragma unroll
        for (int kq = 0; kq < 4; ++kq) {
            G2_W3STEP(kq * 4 + 0, hA.x);
            G2_W3STEP(kq * 4 + 1, hA.y);
            G2_W3STEP(kq * 4 + 2, hA.z);
            G2_W3STEP(kq * 4 + 3, hA.w);
        }
#pragma unroll
        for (int kq = 0; kq < 4; ++kq) {
            G2_W3STEP(16 + kq * 4 + 0, hB.x);
            G2_W3STEP(16 + kq * 4 + 1, hB.y);
            G2_W3STEP(16 + kq * 4 + 2, hB.z);
            G2_W3STEP(16 + kq * 4 + 3, hB.w);
        }
#undef G2_W3STEP
        float4 outv;
        outv.x = dd * t3.x; outv.y = dd * t3.y; outv.z = dd * t3.z; outv.w = dd * t3.w;
        reinterpret_cast<float4*>(tt3)[(size_t)d * 4 + cc] = outv;
    }
}

// ---------------- layer-3 gather: 2-STAGE rotating quad pipeline -> tt4 ----------------
__global__ __launch_bounds__(256) void gather3t4_kernel(const unsigned int* __restrict__ csr,
                                                        const unsigned int* __restrict__ off,
                                                        const unsigned int* __restrict__ deg,
                                                        const float* __restrict__ dinv,
                                                        const float* __restrict__ tt3,
                                                        const float* __restrict__ b3, const float* __restrict__ W4,
                                                        float* __restrict__ tt4, int N) {
    int tid = blockIdx.x * 256 + threadIdx.x;
    int d = tid >> 2, l = tid & 3;
    if (d >= N) return;
    float dd = dinv[d];
    unsigned int o = off[d], n = deg[d];
    const float4* t34 = reinterpret_cast<const float4*>(tt3);
    float4 acc = t34[(size_t)d * 4 + l];   // self term
    float4 acc1 = make_float4(0.f, 0.f, 0.f, 0.f);
    unsigned int Q = n >> 2;               // full quads
    unsigned int k = Q << 2;
    if (Q >= 2) {
        unsigned int a0 = csr[o], a1 = csr[o + 1], a2 = csr[o + 2], a3 = csr[o + 3];
        unsigned int b0 = csr[o + 4], b1 = csr[o + 5], b2 = csr[o + 6], b3i = csr[o + 7];
        float4 v0 = t34[(size_t)a0 * 4 + l];
        float4 v1 = t34[(size_t)a1 * 4 + l];
        float4 v2 = t34[(size_t)a2 * 4 + l];
        float4 v3 = t34[(size_t)a3 * 4 + l];
        for (unsigned int j = 0; j + 2 < Q; ++j) {
            unsigned int base = o + 4 * j;
            unsigned int nb0 = csr[base + 8], nb1 = csr[base + 9];
            unsigned int nb2 = csr[base + 10], nb3 = csr[base + 11];
            float4 w0 = t34[(size_t)b0 * 4 + l];
            float4 w1 = t34[(size_t)b1 * 4 + l];
            float4 w2 = t34[(size_t)b2 * 4 + l];
            float4 w3 = t34[(size_t)b3i * 4 + l];
            acc.x += v0.x + v2.x; acc.y += v0.y + v2.y; acc.z += v0.z + v2.z; acc.w += v0.w + v2.w;
            acc1.x += v1.x + v3.x; acc1.y += v1.y + v3.y; acc1.z += v1.z + v3.z; acc1.w += v1.w + v3.w;
            v0 = w0; v1 = w1; v2 = w2; v3 = w3;
            b0 = nb0; b1 = nb1; b2 = nb2; b3i = nb3;
        }
        float4 w0 = t34[(size_t)b0 * 4 + l];
        float4 w1 = t34[(size_t)b1 * 4 + l];
        float4 w2 = t34[(size_t)b2 * 4 + l];
        float4 w3 = t34[(size_t)b3i * 4 + l];
        acc.x += v0.x + v2.x; acc.y += v0.y + v2.y; acc.z += v0.z + v2.z; acc.w += v0.w + v2.w;
        acc1.x += v1.x + v3.x; acc1.y += v1.y + v3.y; acc1.z += v1.z + v3.z; acc1.w += v1.w + v3.w;
        acc.x += w0.x + w2.x; acc.y += w0.y + w2.y; acc.z += w0.z + w2.z; acc.w += w0.w + w2.w;
        acc1.x += w1.x + w3.x; acc1.y += w1.y + w3.y; acc1.z += w1.z + w3.z; acc1.w += w1.w + w3.w;
    } else if (Q == 1) {
        unsigned int a0 = csr[o], a1 = csr[o + 1], a2 = csr[o + 2], a3 = csr[o + 3];
        float4 v0 = t34[(size_t)a0 * 4 + l];
        float4 v1 = t34[(size_t)a1 * 4 + l];
        float4 v2 = t34[(size_t)a2 * 4 + l];
        float4 v3 = t34[(size_t)a3 * 4 + l];
        acc.x += v0.x + v2.x; acc.y += v0.y + v2.y; acc.z += v0.z + v2.z; acc.w += v0.w + v2.w;
        acc1.x += v1.x + v3.x; acc1.y += v1.y + v3.y; acc1.z += v1.z + v3.z; acc1.w += v1.w + v3.w;
    }
    for (; k < n; ++k) {
        float4 v0 = t34[(size_t)csr[o + k] * 4 + l];
        acc.x += v0.x; acc.y += v0.y; acc.z += v0.z; acc.w += v0.w;
    }
    acc.x += acc1.x; acc.y += acc1.y; acc.z += acc1.z; acc.w += acc1.w;
    float4 b3v = reinterpret_cast<const float4*>(b3)[l];
    float4 w4v = reinterpret_cast<const float4*>(W4)[l];
    float v = fmaxf(fmaf(dd, acc.x, b3v.x), 0.f) * w4v.x;
    v = fmaf(fmaxf(fmaf(dd, acc.y, b3v.y), 0.f), w4v.y, v);
    v = fmaf(fmaxf(fmaf(dd, acc.z, b3v.z), 0.f), w4v.z, v);
    v = fmaf(fmaxf(fmaf(dd, acc.w, b3v.w), 0.f), w4v.w, v);
    v += __shfl_xor(v, 1, 4);
    v += __shfl_xor(v, 2, 4);
    if (l == 0) tt4[d] = dd * v;
}

// ---------------- layer-4 scalar gather (2-stage pipeline) -> out ----------------
__global__ void gather4_kernel(const unsigned int* __restrict__ csr, const unsigned int* __restrict__ off,
                               const unsigned int* __restrict__ deg, const float* __restrict__ dinv,
                               const float* __restrict__ tt, const float* __restrict__ b4,
                               float* __restrict__ out, int N) {
    int tid = blockIdx.x * blockDim.x + threadIdx.x;
    int i = tid >> 2, l = tid & 3;
    if (i >= N) return;
    unsigned int o = off[i], n = deg[i];
    float acc0 = 0.f, acc1 = 0.f;
    unsigned int k = l;
    if (k < n) {
        unsigned int c0 = csr[o + k];
        unsigned int k2 = k + 4;
        for (; k2 < n; k2 += 4) {
            unsigned int c1 = csr[o + k2];
            float v = tt[c0];
            if ((k2 - l) & 4u) acc1 += v; else acc0 += v;
            c0 = c1;
        }
        float v = tt[c0];
        if ((k2 - l) & 4u) acc1 += v; else acc0 += v;
    }
    float acc = acc0 + acc1;
    acc += __shfl_xor(acc, 1, 4);
    acc += __shfl_xor(acc, 2, 4);
    if (l == 0) out[i] = dinv[i] * (acc + tt[i]) + b4[0];
}

extern "C" void kernel_launch(void* const* d_in, const int* in_sizes, int n_in,
                              void* d_out, int out_size, void* d_ws, size_t ws_size,
                              hipStream_t stream) {
    const float* x  = (const float*)d_in[0];
    const int* eidx = (const int*)d_in[1];
    const float* W1 = (const float*)d_in[2];
    const float* b1 = (const float*)d_in[3];
    const float* W2 = (const float*)d_in[4];
    const float* b2 = (const float*)d_in[5];
    const float* W3 = (const float*)d_in[6];
    const float* b3 = (const float*)d_in[7];
    const float* W4 = (const float*)d_in[8];
    const float* b4 = (const float*)d_in[9];
    float* out = (float*)d_out;

    const int N = in_sizes[0];         // 100000
    const int E = in_sizes[1] / 2;     // 3200000
    const int* src = eidx;
    const int* dst = eidx + E;
    const int NB = (N + NPB - 1) >> NPB_SHIFT;   // 391 buckets

    char* ws = (char*)d_ws;
    unsigned int* bcur  = (unsigned int*)ws;  ws += MAXB * 4;
    float* tvals = (float*)ws;                ws += 64 * 4;
    float* Alut  = (float*)ws;                ws += 65 * 32 * 4;
    float* Blut  = (float*)ws;                ws += 65 * 32 * 4;
    unsigned int* off = (unsigned int*)ws;    ws += (size_t)N * 4;
    unsigned int* deg = (unsigned int*)ws;    ws += (size_t)N * 4;
    float* dinv = (float*)ws;                 ws += (size_t)N * 4;
    float* ttx  = (float*)ws;                 ws += (size_t)N * 4;
    float* tt4  = (float*)ws;                 ws += (size_t)N * 4;
    uint4* recs = (uint4*)ws;                 ws += (size_t)N * 16;
    unsigned int* csr = (unsigned int*)ws;    ws += (size_t)NB * BCAP * 4;   // padded CSR (14.4MB)
    unsigned int* staged = (unsigned int*)ws; // padded staged; tt3 (6.4MB) aliases it
    float* tt3 = (float*)staged;              // staged dead after build_csr

    const int nPartBlocks = (E + EPB - 1) / EPB;   // 782

    lut_kernel<<<65, 256, 0, stream>>>(W1, b1, W2, Alut, Blut, tvals, bcur, NB);
    partition_kernel<<<nPartBlocks, 256, 0, stream>>>(src, dst, bcur, staged, E, NB);
    build_csr_kernel<<<NB, 256, 0, stream>>>(staged, bcur, x, csr, off, deg, dinv, ttx, N);

    gather1_kernel<<<((size_t)N * 4 + 255) / 256, 256, 0, stream>>>(csr, off, deg, dinv, ttx, tvals, recs, N);
    gather2t3_kernel<<<(N + 64 * G2_ITERS - 1) / (64 * G2_ITERS), 256, 0, stream>>>(csr, off, deg, dinv, recs, Alut, Blut, b2, W3, tt3, N);
    gather3t4_kernel<<<((size_t)N * 4 + 255) / 256, 256, 0, stream>>>(csr, off, deg, dinv, tt3, b3, W4, tt4, N);
    gather4_kernel<<<((size_t)N * 4 + 255) / 256, 256, 0, stream>>>(csr, off, deg, dinv, tt4, b4, out, N);
}